// Round 7
// baseline (1418.729 us; speedup 1.0000x reference)
//
#include <hip/hip_runtime.h>
#include <hip/hip_bf16.h>
#include <math.h>

typedef short bf16x8 __attribute__((ext_vector_type(8)));
typedef float f32x4 __attribute__((ext_vector_type(4)));

#define B_   128
#define T_   800
#define E_   100
#define HC   192       // 2H
#define OUTV 102400    // B*C*O

__device__ inline float squash_scale(float n2) {
    return (n2 / (n2 + 1.f)) * rsqrtf(fmaxf(n2, 1e-30f));
}

__device__ inline unsigned short bf16_bits(float x) {
    __hip_bfloat16 h = __float2bfloat16(x);
    return *(unsigned short*)&h;
}

__device__ inline unsigned int pack_bf16x2(float a, float b) {
    return (unsigned int)bf16_bits(a) | ((unsigned int)bf16_bits(b) << 16);
}

// split x into hi (bf16) + lo (bf16 of residual)
__device__ inline void split_hilo(float x, unsigned short& hi, unsigned short& lo) {
    __hip_bfloat16 h = __float2bfloat16(x);
    float hf = __bfloat162float(h);
    hi = *(unsigned short*)&h;
    __hip_bfloat16 l = __float2bfloat16(x - hf);
    lo = *(unsigned short*)&l;
}

// ---------------------------------------------------------------------------
// Kernel A: gi = gather(emb, tokens[chunk]) @ wih^T + bih  for ONE direction.
// ---------------------------------------------------------------------------
__global__ __launch_bounds__(256) void k_gi(const int* __restrict__ tokens,
        const float* __restrict__ emb,
        const float* __restrict__ wih,
        const float* __restrict__ bih,
        __hip_bfloat16* __restrict__ gi,
        int t0, int TC)
{
    const int m0 = blockIdx.x * 64;
    const int n0 = blockIdx.y * 64;      // 0,64,128,192,256
    const int tid = threadIdx.x;
    __shared__ __align__(16) unsigned short At[64 * 136];   // 64 x 128, stride 136
    __shared__ __align__(16) unsigned short Bhi[64 * 136];
    __shared__ __align__(16) unsigned short Blo[64 * 136];
    __shared__ int tok[64];
    if (tid < 64) {
        int cr = m0 + tid;
        tok[tid] = tokens[(cr / TC) * T_ + t0 + (cr % TC)];
    }
    __syncthreads();
    for (int idx = tid; idx < 64 * 64; idx += 256) {
        int r = idx >> 6, p = idx & 63;          // p = column pair
        unsigned int v = 0;
        if (p < 50) {
            float2 f = *(const float2*)(emb + (size_t)tok[r] * E_ + 2 * p);
            v = pack_bf16x2(f.x, f.y);
        }
        *(unsigned int*)(&At[r * 136 + 2 * p]) = v;
    }
    for (int idx = tid; idx < 64 * 64; idx += 256) {
        int nn = idx >> 6, p = idx & 63;
        int gc = n0 + nn;
        unsigned int vh = 0, vl = 0;
        if (p < 50 && gc < 288) {
            float2 f = *(const float2*)(wih + (size_t)gc * E_ + 2 * p);
            unsigned short h0, l0, h1, l1;
            split_hilo(f.x, h0, l0);
            split_hilo(f.y, h1, l1);
            vh = (unsigned int)h0 | ((unsigned int)h1 << 16);
            vl = (unsigned int)l0 | ((unsigned int)l1 << 16);
        }
        *(unsigned int*)(&Bhi[nn * 136 + 2 * p]) = vh;
        *(unsigned int*)(&Blo[nn * 136 + 2 * p]) = vl;
    }
    __syncthreads();
    const int w = tid >> 6, l = tid & 63;
    const int lr = l & 15, quad = l >> 4;
    f32x4 z4 = {0.f, 0.f, 0.f, 0.f};
    f32x4 acc[4];
#pragma unroll
    for (int i = 0; i < 4; ++i) acc[i] = z4;
#pragma unroll
    for (int kk = 0; kk < 4; ++kk) {
        bf16x8 af = *(const bf16x8*)(&At[(w * 16 + lr) * 136 + kk * 32 + quad * 8]);
#pragma unroll
        for (int ns = 0; ns < 4; ++ns) {
            bf16x8 bh = *(const bf16x8*)(&Bhi[(ns * 16 + lr) * 136 + kk * 32 + quad * 8]);
            bf16x8 bl = *(const bf16x8*)(&Blo[(ns * 16 + lr) * 136 + kk * 32 + quad * 8]);
            acc[ns] = __builtin_amdgcn_mfma_f32_16x16x32_bf16(af, bh, acc[ns], 0, 0, 0);
            acc[ns] = __builtin_amdgcn_mfma_f32_16x16x32_bf16(af, bl, acc[ns], 0, 0, 0);
        }
    }
#pragma unroll
    for (int ns = 0; ns < 4; ++ns) {
        int gcol = n0 + ns * 16 + lr;
        if (gcol < 288) {
            float bias = bih[gcol];
#pragma unroll
            for (int r2 = 0; r2 < 4; ++r2) {
                int grow = m0 + w * 16 + quad * 4 + r2;
                gi[(size_t)grow * 288 + gcol] = __float2bfloat16(acc[ns][r2] + bias);
            }
        }
    }
}

// ---------------------------------------------------------------------------
// Kernel B (merged): GRU recurrence, BOTH directions in one launch.
// Grid (800, 2) x 288 threads. Thread j holds whh row j fp32 (exact).
// h broadcast copy in LDS as packed bf16 (halves ds_read traffic);
// per-unit fp32 state kept in the updater thread's register.
// gv software-prefetched one step ahead.
// ---------------------------------------------------------------------------
__global__ __launch_bounds__(288) void k_gru2(
        const __hip_bfloat16* __restrict__ gi0,
        const __hip_bfloat16* __restrict__ gi1,
        const float* __restrict__ whh_f, const float* __restrict__ whh_b,
        const float* __restrict__ bhh_f, const float* __restrict__ bhh_b,
        __hip_bfloat16* __restrict__ hout)
{
    const int n = blockIdx.x;            // 0..799 chain (t index)
    const int u = blockIdx.y;            // 0 fwd, 1 bwd
    const int j = threadIdx.x;           // 0..287
    const __hip_bfloat16* gi = u ? gi1 : gi0;
    const float* whh = u ? whh_b : whh_f;
    const float* bhh = u ? bhh_b : bhh_f;
    __shared__ __align__(16) unsigned int hp[48];     // 96 bf16 packed
    __shared__ float bufz[96], bufni[96], bufnh[96];
    float w[96];
    {
        const float* wr = whh + (size_t)j * 96;
#pragma unroll
        for (int k = 0; k < 96; ++k) w[k] = wr[k];
    }
    const float bj = bhh[j];
    if (j < 48) hp[j] = 0u;
    float hj = 0.f;                      // private fp32 state (valid for j<96)
    __syncthreads();
    const ptrdiff_t stride = (ptrdiff_t)T_ * 288;
    const __hip_bfloat16* gp = gi + (size_t)(u ? 127 : 0) * stride + (size_t)n * 288 + j;
    const ptrdiff_t dstep = u ? -stride : stride;
    float gv = (float)*gp;
    for (int s = 0; s < 128; ++s) {
        const int i = u ? (127 - s) : s;
        const __hip_bfloat16* gpn = (s < 127) ? (gp + dstep) : gp;
        float gvn = (float)*gpn;         // prefetch next step's gv (h-independent)
        gp = gpn;
        // gh = dot(h, w_row_j): packed-bf16 broadcast reads, 8 indep accum lanes
        float2 a0 = {0.f, 0.f}, a1 = {0.f, 0.f}, a2 = {0.f, 0.f}, a3 = {0.f, 0.f};
        const uint4* h4 = (const uint4*)hp;          // 12 x uint4 = 96 bf16
#pragma unroll
        for (int q = 0; q < 12; ++q) {
            uint4 pk = h4[q];
            const float* wq = &w[8 * q];
            float2 p0 = { __uint_as_float(pk.x << 16), __uint_as_float(pk.x & 0xffff0000u) };
            float2 p1 = { __uint_as_float(pk.y << 16), __uint_as_float(pk.y & 0xffff0000u) };
            float2 p2 = { __uint_as_float(pk.z << 16), __uint_as_float(pk.z & 0xffff0000u) };
            float2 p3 = { __uint_as_float(pk.w << 16), __uint_as_float(pk.w & 0xffff0000u) };
            a0.x += p0.x * wq[0]; a0.y += p0.y * wq[1];
            a1.x += p1.x * wq[2]; a1.y += p1.y * wq[3];
            a2.x += p2.x * wq[4]; a2.y += p2.y * wq[5];
            a3.x += p3.x * wq[6]; a3.y += p3.y * wq[7];
        }
        float gh = bj + ((a0.x + a0.y) + (a1.x + a1.y)) + ((a2.x + a2.y) + (a3.x + a3.y));
        float rsum = gv + gh;            // r-gate pre-activation (valid for j<96)
        if (j >= 192)      { bufni[j - 192] = gv; bufnh[j - 192] = gh; }
        else if (j >= 96)  { bufz[j - 96] = rsum; }
        __syncthreads();
        if (j < 96) {
            float rg = 1.f / (1.f + __expf(-rsum));
            float zg = 1.f / (1.f + __expf(-bufz[j]));
            float ng = tanhf(bufni[j] + rg * bufnh[j]);
            hj = (1.f - zg) * ng + zg * hj;
            ((__hip_bfloat16*)hp)[j] = __float2bfloat16(hj);   // b16 write, own lane
            hout[((size_t)i * T_ + n) * HC + u * 96 + j] = __float2bfloat16(hj);
        }
        gv = gvn;
        __syncthreads();
    }
}

// ---------------------------------------------------------------------------
// Kernel B-fallback: chunked per-direction GRU (used only if ws is small).
// ---------------------------------------------------------------------------
__global__ __launch_bounds__(288) void k_gru_seq(
        const __hip_bfloat16* __restrict__ gi,
        const float* __restrict__ whh,
        const float* __restrict__ bhh,
        __hip_bfloat16* __restrict__ hout,
        int t0, int TC, int u)
{
    const int nl = blockIdx.x;
    const int j = threadIdx.x;           // 0..287
    __shared__ __align__(16) float h_l[96];
    __shared__ float bufz[96], bufni[96], bufnh[96];
    float w[96];
    {
        const float* wr = whh + (size_t)j * 96;
#pragma unroll
        for (int k = 0; k < 96; ++k) w[k] = wr[k];
    }
    const float bj = bhh[j];
    if (j < 96) h_l[j] = 0.f;
    __syncthreads();
    for (int s = 0; s < 128; ++s) {
        const int i = u ? (127 - s) : s;
        const float gv = (float)gi[((size_t)i * TC + nl) * 288 + j];
        float gh = bj;
        const float4* h4 = (const float4*)(&h_l[0]);
#pragma unroll
        for (int q = 0; q < 24; ++q) {
            float4 hv = h4[q];
            gh += hv.x * w[4 * q] + hv.y * w[4 * q + 1] + hv.z * w[4 * q + 2] + hv.w * w[4 * q + 3];
        }
        if (j >= 192)      { bufni[j - 192] = gv; bufnh[j - 192] = gh; }
        else if (j >= 96)  { bufz[j - 96] = gv + gh; }
        __syncthreads();
        if (j < 96) {
            float rg = 1.f / (1.f + __expf(-(gv + gh)));
            float zg = 1.f / (1.f + __expf(-bufz[j]));
            float ng = tanhf(bufni[j] + rg * bufnh[j]);
            float hn = (1.f - zg) * ng + zg * h_l[j];
            h_l[j] = hn;
            hout[((size_t)i * T_ + (t0 + nl)) * HC + u * 96 + j] = __float2bfloat16(hn);
        }
        __syncthreads();
    }
}

// ---------------------------------------------------------------------------
// Kernel C1: tt = tanh(h @ A1 + b1)    M=102400, K=192, N=50 (pad 64), MFMA
// ---------------------------------------------------------------------------
__global__ __launch_bounds__(256) void k_att1(
        const __hip_bfloat16* __restrict__ h,
        const float* __restrict__ A1,
        const float* __restrict__ b1,
        __hip_bfloat16* __restrict__ tt)
{
    const int m0 = blockIdx.x * 64;      // 1600 blocks
    const int tid = threadIdx.x;
    __shared__ __align__(16) unsigned short At[64 * 200];
    __shared__ __align__(16) unsigned short Bhi[64 * 200];
    __shared__ __align__(16) unsigned short Blo[64 * 200];
    for (int idx = tid; idx < 64 * 96; idx += 256) {
        int r = idx / 96, p = idx - r * 96;
        unsigned int v = *(const unsigned int*)((const unsigned short*)h + ((size_t)(m0 + r) * HC + 2 * p));
        *(unsigned int*)(&At[r * 200 + 2 * p]) = v;
    }
    for (int idx = tid; idx < 64 * 192; idx += 256) {
        int nn = idx / 192, k = idx - nn * 192;
        unsigned short vh = 0, vl = 0;
        if (nn < 50) split_hilo(A1[k * 50 + nn], vh, vl);   // transpose A1 -> B[n][k]
        Bhi[nn * 200 + k] = vh;
        Blo[nn * 200 + k] = vl;
    }
    __syncthreads();
    const int w = tid >> 6, l = tid & 63;
    const int lr = l & 15, quad = l >> 4;
    f32x4 z4 = {0.f, 0.f, 0.f, 0.f};
    f32x4 acc[4];
#pragma unroll
    for (int i = 0; i < 4; ++i) acc[i] = z4;
#pragma unroll
    for (int kk = 0; kk < 6; ++kk) {
        bf16x8 af = *(const bf16x8*)(&At[(w * 16 + lr) * 200 + kk * 32 + quad * 8]);
#pragma unroll
        for (int ns = 0; ns < 4; ++ns) {
            bf16x8 bh = *(const bf16x8*)(&Bhi[(ns * 16 + lr) * 200 + kk * 32 + quad * 8]);
            bf16x8 bl = *(const bf16x8*)(&Blo[(ns * 16 + lr) * 200 + kk * 32 + quad * 8]);
            acc[ns] = __builtin_amdgcn_mfma_f32_16x16x32_bf16(af, bh, acc[ns], 0, 0, 0);
            acc[ns] = __builtin_amdgcn_mfma_f32_16x16x32_bf16(af, bl, acc[ns], 0, 0, 0);
        }
    }
#pragma unroll
    for (int ns = 0; ns < 4; ++ns) {
        int col = ns * 16 + lr;
        if (col < 50) {
            float bias = b1[col];
#pragma unroll
            for (int r2 = 0; r2 < 4; ++r2) {
                int grow = m0 + w * 16 + quad * 4 + r2;
                tt[(size_t)grow * 50 + col] = __float2bfloat16(tanhf(acc[ns][r2] + bias));
            }
        }
    }
}

// ---------------------------------------------------------------------------
// Kernel C2: att = softmax(tt @ A2 + b2, axis=-1)   one row per lane
// ---------------------------------------------------------------------------
__global__ __launch_bounds__(256) void k_att2(
        const __hip_bfloat16* __restrict__ tt,
        const float* __restrict__ A2,
        const float* __restrict__ b2,
        float* __restrict__ att)
{
    __shared__ float A2l[600];
    __shared__ float b2l[12];
    const int tid = threadIdx.x;
    for (int idx = tid; idx < 600; idx += 256) A2l[idx] = A2[idx];
    if (tid < 12) b2l[tid] = b2[tid];
    __syncthreads();
    const int row = blockIdx.x * 256 + tid;    // 400*256 == 102400 exact
    float acc[12];
#pragma unroll
    for (int r = 0; r < 12; ++r) acc[r] = b2l[r];
    const __hip_bfloat16* trow = tt + (size_t)row * 50;
    for (int jj = 0; jj < 50; ++jj) {
        float tv = (float)trow[jj];
#pragma unroll
        for (int r = 0; r < 12; ++r) acc[r] += tv * A2l[jj * 12 + r];
    }
    float mx = acc[0];
#pragma unroll
    for (int r = 1; r < 12; ++r) mx = fmaxf(mx, acc[r]);
    float sm = 0.f;
#pragma unroll
    for (int r = 0; r < 12; ++r) { acc[r] = __expf(acc[r] - mx); sm += acc[r]; }
    float inv = 1.f / sm;
#pragma unroll
    for (int r = 0; r < 12; ++r) att[(size_t)row * 12 + r] = acc[r] * inv;
}

// ---------------------------------------------------------------------------
// Kernel D1: per-batch pooling: m = att^T h, g = att^T att, squash -> v0, nrm
// ---------------------------------------------------------------------------
__global__ __launch_bounds__(256) void k_pool(
        const __hip_bfloat16* __restrict__ h,
        const float* __restrict__ att,
        float* __restrict__ v0g,      // [128][12][192] fp32
        float* __restrict__ norms)
{
    const int b = blockIdx.x;
    const int tid = threadIdx.x;
    __shared__ __align__(16) unsigned short hT[64 * 192];
    __shared__ float attT[64 * 12];
    __shared__ float m_l[12 * 192];
    __shared__ float g_l[144];
    __shared__ float scl[12];

    float macc[12];
#pragma unroll
    for (int r = 0; r < 12; ++r) macc[r] = 0.f;
    float gacc[3] = {0.f, 0.f, 0.f};

    for (int t0 = 0; t0 < T_; t0 += 64) {
        __syncthreads();
        for (int idx = tid; idx < 64 * 96; idx += 256) {
            int rr = idx / 96, p = idx - rr * 96;
            unsigned int v = 0;
            if (t0 + rr < T_)   // zero-pad tail tile (800 = 12*64 + 32)
                v = *(const unsigned int*)((const unsigned short*)h +
                                ((size_t)(b * T_ + t0 + rr) * HC + 2 * p));
            *(unsigned int*)(&hT[rr * 192 + 2 * p]) = v;
        }
        for (int idx = tid; idx < 64 * 12; idx += 256) {
            int rr = idx / 12;
            attT[idx] = (t0 + rr < T_) ? att[(size_t)(b * T_ + t0) * 12 + idx] : 0.f;
        }
        __syncthreads();
        if (tid < 192) {
            for (int t2 = 0; t2 < 64; ++t2) {
                float hv = (float)(*(const __hip_bfloat16*)(&hT[t2 * 192 + tid]));
#pragma unroll
                for (int r = 0; r < 12; ++r) macc[r] += hv * attT[t2 * 12 + r];
            }
        } else {
            int e = tid - 192;
#pragma unroll
            for (int q = 0; q < 3; ++q) {
                int idx = e + 64 * q;
                if (idx < 144) {
                    int rr = idx / 12, ss = idx - rr * 12;
                    float s2 = 0.f;
                    for (int t2 = 0; t2 < 64; ++t2) s2 += attT[t2 * 12 + rr] * attT[t2 * 12 + ss];
                    gacc[q] += s2;
                }
            }
        }
    }
    __syncthreads();
    if (tid < 192) { for (int r = 0; r < 12; ++r) m_l[r * 192 + tid] = macc[r]; }
    else {
        int e = tid - 192;
#pragma unroll
        for (int q = 0; q < 3; ++q) { int idx = e + 64 * q; if (idx < 144) g_l[idx] = gacc[q]; }
    }
    __syncthreads();
    if (tid == 0) {
        float s2 = 0.f;
        for (int idx = 0; idx < 144; ++idx) {
            float v = g_l[idx] - ((idx / 12 == idx % 12) ? 1.f : 0.f);
            s2 += v * v;
        }
        norms[b] = sqrtf(s2);
    }
    if (tid < 12) {
        float n2 = 0.f;
        for (int i = 0; i < 192; ++i) { float v = m_l[tid * 192 + i]; n2 += v * v; }
        scl[tid] = squash_scale(n2);
    }
    __syncthreads();
    if (tid < 192) {
#pragma unroll
        for (int r = 0; r < 12; ++r)
            v0g[((size_t)b * 12 + r) * 192 + tid] = m_l[r * 192 + tid] * scl[r];
    }
}

// ---------------------------------------------------------------------------
// Kernel D2: u_hat GEMM per r: [128 x 192] @ [192 x 800]. Grid (12, 2, 13).
// ---------------------------------------------------------------------------
__global__ __launch_bounds__(256) void k_uhat(
        const float* __restrict__ v0g,
        const float* __restrict__ Wc,
        float* __restrict__ u_hat)    // [128][12][800] fp32
{
    const int r  = blockIdx.x;           // 0..11
    const int m0 = blockIdx.y * 64;      // 0,64
    const int n0 = blockIdx.z * 64;      // 0..768 (tail tile 32 valid)
    const int tid = threadIdx.x;
    __shared__ __align__(16) unsigned short At[64 * 200];
    __shared__ __align__(16) unsigned short Bt[64 * 200];
    for (int idx = tid; idx < 64 * 96; idx += 256) {
        int row = idx / 96, p = idx - row * 96;
        float2 f = *(const float2*)(v0g + ((size_t)(m0 + row) * 12 + r) * 192 + 2 * p);
        *(unsigned int*)(&At[row * 200 + 2 * p]) = pack_bf16x2(f.x, f.y);
    }
    for (int idx = tid; idx < 192 * 64; idx += 256) {
        int k = idx >> 6, nn = idx & 63;
        unsigned short v = 0;
        if (n0 + nn < 800) v = bf16_bits(Wc[((size_t)r * 192 + k) * 800 + n0 + nn]);
        Bt[nn * 200 + k] = v;
    }
    __syncthreads();
    const int w = tid >> 6, l = tid & 63;
    const int lr = l & 15, quad = l >> 4;
    f32x4 z4 = {0.f, 0.f, 0.f, 0.f};
    f32x4 acc[4];
#pragma unroll
    for (int i = 0; i < 4; ++i) acc[i] = z4;
#pragma unroll
    for (int kk = 0; kk < 6; ++kk) {
        bf16x8 af = *(const bf16x8*)(&At[(w * 16 + lr) * 200 + kk * 32 + quad * 8]);
#pragma unroll
        for (int ns = 0; ns < 4; ++ns) {
            bf16x8 bv = *(const bf16x8*)(&Bt[(ns * 16 + lr) * 200 + kk * 32 + quad * 8]);
            acc[ns] = __builtin_amdgcn_mfma_f32_16x16x32_bf16(af, bv, acc[ns], 0, 0, 0);
        }
    }
#pragma unroll
    for (int ns = 0; ns < 4; ++ns) {
        int cco = n0 + ns * 16 + lr;
        if (cco < 800) {
#pragma unroll
            for (int r2 = 0; r2 < 4; ++r2) {
                int brow = m0 + w * 16 + quad * 4 + r2;
                u_hat[((size_t)brow * 12 + r) * 800 + cco] = acc[ns][r2];
            }
        }
    }
}

// ---------------------------------------------------------------------------
// Kernel D3: dynamic routing per batch (u_hat in LDS), 3 iterations, write v.
// ---------------------------------------------------------------------------
__global__ __launch_bounds__(256) void k_route(
        const float* __restrict__ u_hat,
        float* __restrict__ out)
{
    const int b = blockIdx.x;
    const int tid = threadIdx.x;
    __shared__ __align__(16) float u_l[9600];
    __shared__ float blogl[600];
    __shared__ float c_l[600];
    __shared__ float s_l[800];
    __shared__ float v_l[800];
    __shared__ float scl[64];
    {
        const float4* src = (const float4*)(u_hat + (size_t)b * 9600);
        float4* dst = (float4*)u_l;
        for (int e = tid; e < 2400; e += 256) dst[e] = src[e];
    }
    for (int e = tid; e < 600; e += 256) blogl[e] = 0.f;
    __syncthreads();
    for (int it = 0; it < 3; ++it) {
        if (tid < 12) {
            float mx = -1e30f;
            for (int cc = 0; cc < 50; ++cc) mx = fmaxf(mx, blogl[tid * 50 + cc]);
            float sm = 0.f;
            for (int cc = 0; cc < 50; ++cc) {
                float e2 = __expf(blogl[tid * 50 + cc] - mx);
                c_l[tid * 50 + cc] = e2; sm += e2;
            }
            float inv = 1.f / sm;
            for (int cc = 0; cc < 50; ++cc) c_l[tid * 50 + cc] *= inv;
        }
        __syncthreads();
        for (int e = tid; e < 800; e += 256) {
            int cc = e >> 4;
            float sv = 0.f;
#pragma unroll
            for (int r = 0; r < 12; ++r) sv += c_l[r * 50 + cc] * u_l[r * 800 + e];
            s_l[e] = sv;
        }
        __syncthreads();
        for (int cc = tid; cc < 50; cc += 256) {
            float n2 = 0.f;
#pragma unroll
            for (int o = 0; o < 16; ++o) { float v = s_l[cc * 16 + o]; n2 += v * v; }
            scl[cc] = squash_scale(n2);
        }
        __syncthreads();
        for (int e = tid; e < 800; e += 256) v_l[e] = s_l[e] * scl[e >> 4];
        __syncthreads();
        if (it < 2) {
            for (int e = tid; e < 600; e += 256) {
                int cc = e % 50;
                float dd = 0.f;
#pragma unroll
                for (int o = 0; o < 16; ++o) dd += u_l[e * 16 + o] * v_l[cc * 16 + o];
                blogl[e] += dd;
            }
            __syncthreads();
        }
    }
    for (int e = tid; e < 800; e += 256) out[(size_t)b * 800 + e] = v_l[e];
}

// ---------------------------------------------------------------------------
// Kernel E: att_reg = mean(norms)
// ---------------------------------------------------------------------------
__global__ void k_reg(const float* __restrict__ norms, float* __restrict__ out)
{
    const int l = threadIdx.x;           // 64
    float v = norms[l] + norms[l + 64];
#pragma unroll
    for (int off = 32; off; off >>= 1) v += __shfl_down(v, off);
    if (l == 0) out[OUTV] = v * (1.f / 128.f);
}

// ---------------------------------------------------------------------------
extern "C" void kernel_launch(void* const* d_in, const int* in_sizes, int n_in,
                              void* d_out, int out_size, void* d_ws, size_t ws_size,
                              hipStream_t stream) {
    const int*   tokens = (const int*)d_in[0];
    const float* emb    = (const float*)d_in[1];
    const float* wih_f  = (const float*)d_in[2];
    const float* whh_f  = (const float*)d_in[3];
    const float* bih_f  = (const float*)d_in[4];
    const float* bhh_f  = (const float*)d_in[5];
    const float* wih_b  = (const float*)d_in[6];
    const float* whh_b  = (const float*)d_in[7];
    const float* bih_b  = (const float*)d_in[8];
    const float* bhh_b  = (const float*)d_in[9];
    const float* A1     = (const float*)d_in[10];
    const float* b1     = (const float*)d_in[11];
    const float* A2     = (const float*)d_in[12];
    const float* b2     = (const float*)d_in[13];
    const float* Wc     = (const float*)d_in[14];

    const size_t HB = 39321600;                  // hbuf: 102400*192*2 (bf16)
    const size_t GI = 58982400;                  // one direction gi: 128*800*288*2
    char* ws = (char*)d_ws;
    __hip_bfloat16* hbuf = (__hip_bfloat16*)ws;
    float* out = (float*)d_out;

    if (ws_size >= HB + 2 * GI + 11010560) {
        // ---- primary path: both directions resident, single merged GRU ----
        __hip_bfloat16* gi_f = (__hip_bfloat16*)(ws + HB);
        __hip_bfloat16* gi_b = (__hip_bfloat16*)(ws + HB + GI);
        char* tail = ws + HB + 2 * GI;
        __hip_bfloat16* tt   = (__hip_bfloat16*)(ws + HB);   // reuses gi_f after GRU
        float*          att  = (float*)(tail);               //  4,915,200
        float*          nrm  = (float*)(tail + 4915200);     //        512
        float*          v0g  = (float*)(tail + 4915712);     //  1,179,648
        float*          uhat = (float*)(tail + 6095360);     //  4,915,200 -> 11,010,560
        k_gi  <<<dim3(1600, 5), 256, 0, stream>>>(tokens, emb, wih_f, bih_f, gi_f, 0, T_);
        k_gi  <<<dim3(1600, 5), 256, 0, stream>>>(tokens, emb, wih_b, bih_b, gi_b, 0, T_);
        k_gru2<<<dim3(800, 2), 288, 0, stream>>>(gi_f, gi_b, whh_f, whh_b, bhh_f, bhh_b, hbuf);
        k_att1 <<<1600, 256, 0, stream>>>(hbuf, A1, b1, tt);
        k_att2 <<<400, 256, 0, stream>>>(tt, A2, b2, att);
        k_pool <<<128, 256, 0, stream>>>(hbuf, att, v0g, nrm);
        k_uhat <<<dim3(12, 2, 13), 256, 0, stream>>>(v0g, Wc, uhat);
        k_route<<<128, 256, 0, stream>>>(uhat, out);
        k_reg  <<<1, 64, 0, stream>>>(nrm, out);
    } else {
        // ---- fallback: chunked per-direction (round-6 verified path) ----
        char* region2 = ws + HB;
        int TC = (ws_size >= HB + (size_t)128 * 400 * 288 * 2 + 21250560) ? 400 : 200;
        __hip_bfloat16* gi   = (__hip_bfloat16*)region2;
        __hip_bfloat16* tt   = (__hip_bfloat16*)region2;
        float*          att  = (float*)(region2 + 10240000);
        float*          nrm  = (float*)(region2 + 15155200);
        float*          v0g  = (float*)(region2 + 15155712);
        float*          uhat = (float*)(region2 + 16335360);
        for (int u = 0; u < 2; ++u) {
            const float* wih = u ? wih_b : wih_f;
            const float* whh = u ? whh_b : whh_f;
            const float* bih = u ? bih_b : bih_f;
            const float* bhh = u ? bhh_b : bhh_f;
            for (int t0 = 0; t0 < T_; t0 += TC) {
                k_gi <<<dim3(128 * TC / 64, 5), 256, 0, stream>>>(tokens, emb, wih, bih, gi, t0, TC);
                k_gru_seq<<<TC, 288, 0, stream>>>(gi, whh, bhh, hbuf, t0, TC, u);
            }
        }
        k_att1 <<<1600, 256, 0, stream>>>(hbuf, A1, b1, tt);
        k_att2 <<<400, 256, 0, stream>>>(tt, A2, b2, att);
        k_pool <<<128, 256, 0, stream>>>(hbuf, att, v0g, nrm);
        k_uhat <<<dim3(12, 2, 13), 256, 0, stream>>>(v0g, Wc, uhat);
        k_route<<<128, 256, 0, stream>>>(uhat, out);
        k_reg  <<<1, 64, 0, stream>>>(nrm, out);
    }
}

// Round 8
// 1183.402 us; speedup vs baseline: 1.1989x; 1.1989x over previous
//
#include <hip/hip_runtime.h>
#include <hip/hip_bf16.h>
#include <math.h>

typedef short bf16x8 __attribute__((ext_vector_type(8)));
typedef float f32x4 __attribute__((ext_vector_type(4)));

#define B_   128
#define T_   800
#define E_   100
#define HC   192       // 2H
#define OUTV 102400    // B*C*O

__device__ inline float squash_scale(float n2) {
    return (n2 / (n2 + 1.f)) * rsqrtf(fmaxf(n2, 1e-30f));
}

__device__ inline unsigned short bf16_bits(float x) {
    __hip_bfloat16 h = __float2bfloat16(x);
    return *(unsigned short*)&h;
}

__device__ inline unsigned int pack_bf16x2(float a, float b) {
    return (unsigned int)bf16_bits(a) | ((unsigned int)bf16_bits(b) << 16);
}

// split x into hi (bf16) + lo (bf16 of residual)
__device__ inline void split_hilo(float x, unsigned short& hi, unsigned short& lo) {
    __hip_bfloat16 h = __float2bfloat16(x);
    float hf = __bfloat162float(h);
    hi = *(unsigned short*)&h;
    __hip_bfloat16 l = __float2bfloat16(x - hf);
    lo = *(unsigned short*)&l;
}

// ---------------------------------------------------------------------------
// Kernel A: gi = gather(emb, tokens[chunk]) @ wih^T + bih  for ONE direction.
// ---------------------------------------------------------------------------
__global__ __launch_bounds__(256) void k_gi(const int* __restrict__ tokens,
        const float* __restrict__ emb,
        const float* __restrict__ wih,
        const float* __restrict__ bih,
        __hip_bfloat16* __restrict__ gi,
        int t0, int TC)
{
    const int m0 = blockIdx.x * 64;
    const int n0 = blockIdx.y * 64;      // 0,64,128,192,256
    const int tid = threadIdx.x;
    __shared__ __align__(16) unsigned short At[64 * 136];   // 64 x 128, stride 136
    __shared__ __align__(16) unsigned short Bhi[64 * 136];
    __shared__ __align__(16) unsigned short Blo[64 * 136];
    __shared__ int tok[64];
    if (tid < 64) {
        int cr = m0 + tid;
        tok[tid] = tokens[(cr / TC) * T_ + t0 + (cr % TC)];
    }
    __syncthreads();
    for (int idx = tid; idx < 64 * 64; idx += 256) {
        int r = idx >> 6, p = idx & 63;          // p = column pair
        unsigned int v = 0;
        if (p < 50) {
            float2 f = *(const float2*)(emb + (size_t)tok[r] * E_ + 2 * p);
            v = pack_bf16x2(f.x, f.y);
        }
        *(unsigned int*)(&At[r * 136 + 2 * p]) = v;
    }
    for (int idx = tid; idx < 64 * 64; idx += 256) {
        int nn = idx >> 6, p = idx & 63;
        int gc = n0 + nn;
        unsigned int vh = 0, vl = 0;
        if (p < 50 && gc < 288) {
            float2 f = *(const float2*)(wih + (size_t)gc * E_ + 2 * p);
            unsigned short h0, l0, h1, l1;
            split_hilo(f.x, h0, l0);
            split_hilo(f.y, h1, l1);
            vh = (unsigned int)h0 | ((unsigned int)h1 << 16);
            vl = (unsigned int)l0 | ((unsigned int)l1 << 16);
        }
        *(unsigned int*)(&Bhi[nn * 136 + 2 * p]) = vh;
        *(unsigned int*)(&Blo[nn * 136 + 2 * p]) = vl;
    }
    __syncthreads();
    const int w = tid >> 6, l = tid & 63;
    const int lr = l & 15, quad = l >> 4;
    f32x4 z4 = {0.f, 0.f, 0.f, 0.f};
    f32x4 acc[4];
#pragma unroll
    for (int i = 0; i < 4; ++i) acc[i] = z4;
#pragma unroll
    for (int kk = 0; kk < 4; ++kk) {
        bf16x8 af = *(const bf16x8*)(&At[(w * 16 + lr) * 136 + kk * 32 + quad * 8]);
#pragma unroll
        for (int ns = 0; ns < 4; ++ns) {
            bf16x8 bh = *(const bf16x8*)(&Bhi[(ns * 16 + lr) * 136 + kk * 32 + quad * 8]);
            bf16x8 bl = *(const bf16x8*)(&Blo[(ns * 16 + lr) * 136 + kk * 32 + quad * 8]);
            acc[ns] = __builtin_amdgcn_mfma_f32_16x16x32_bf16(af, bh, acc[ns], 0, 0, 0);
            acc[ns] = __builtin_amdgcn_mfma_f32_16x16x32_bf16(af, bl, acc[ns], 0, 0, 0);
        }
    }
#pragma unroll
    for (int ns = 0; ns < 4; ++ns) {
        int gcol = n0 + ns * 16 + lr;
        if (gcol < 288) {
            float bias = bih[gcol];
#pragma unroll
            for (int r2 = 0; r2 < 4; ++r2) {
                int grow = m0 + w * 16 + quad * 4 + r2;
                gi[(size_t)grow * 288 + gcol] = __float2bfloat16(acc[ns][r2] + bias);
            }
        }
    }
}

// ---------------------------------------------------------------------------
// Kernel B (merged): GRU recurrence, BOTH directions in one launch.
// Grid (800, 2) x 288 threads. Thread j holds whh row j in 96 VGPRs —
// __launch_bounds__(288, 1) lifts the VGPR cap so w[96] does NOT spill
// (rounds 5-7 ran with VGPR_Count 64-72 => w spilled to scratch, ~22 GB
// of L2 scratch re-reads per pass = the entire GRU cost).
// fp32 h state in LDS (broadcast reads are conflict-free); 4 accumulators
// break the 96-FMA dependency chain; gv prefetched one step ahead.
// ---------------------------------------------------------------------------
__global__ __launch_bounds__(288, 1) void k_gru2(
        const __hip_bfloat16* __restrict__ gi0,
        const __hip_bfloat16* __restrict__ gi1,
        const float* __restrict__ whh_f, const float* __restrict__ whh_b,
        const float* __restrict__ bhh_f, const float* __restrict__ bhh_b,
        __hip_bfloat16* __restrict__ hout)
{
    const int n = blockIdx.x;            // 0..799 chain (t index)
    const int u = blockIdx.y;            // 0 fwd, 1 bwd
    const int j = threadIdx.x;           // 0..287
    const __hip_bfloat16* gi = u ? gi1 : gi0;
    const float* whh = u ? whh_b : whh_f;
    const float* bhh = u ? bhh_b : bhh_f;
    __shared__ __align__(16) float h_l[96];
    __shared__ float bufz[96], bufni[96], bufnh[96];
    float4 w[24];                        // 96 fp32 weights in registers
    {
        const float4* wr = (const float4*)(whh + (size_t)j * 96);
#pragma unroll
        for (int k = 0; k < 24; ++k) w[k] = wr[k];
    }
    const float bj = bhh[j];
    if (j < 96) h_l[j] = 0.f;
    float hj = 0.f;                      // private fp32 state (valid for j<96)
    __syncthreads();
    const ptrdiff_t stride = (ptrdiff_t)T_ * 288;
    const __hip_bfloat16* gp = gi + (size_t)(u ? 127 : 0) * stride + (size_t)n * 288 + j;
    const ptrdiff_t dstep = u ? -stride : stride;
    float gv = (float)*gp;
    for (int s = 0; s < 128; ++s) {
        const int i = u ? (127 - s) : s;
        const __hip_bfloat16* gpn = (s < 127) ? (gp + dstep) : gp;
        float gvn = (float)*gpn;         // prefetch next step's gv (h-independent)
        gp = gpn;
        // gh = dot(h, w_row_j): fp32 broadcast reads, 4 indep accumulators
        float a0 = 0.f, a1 = 0.f, a2 = 0.f, a3 = 0.f;
        const float4* h4 = (const float4*)(&h_l[0]);
#pragma unroll
        for (int q = 0; q < 6; ++q) {
            float4 h0 = h4[4 * q],     h1 = h4[4 * q + 1];
            float4 h2 = h4[4 * q + 2], h3 = h4[4 * q + 3];
            float4 w0 = w[4 * q],      w1 = w[4 * q + 1];
            float4 w2 = w[4 * q + 2],  w3 = w[4 * q + 3];
            a0 += h0.x * w0.x + h0.y * w0.y + h0.z * w0.z + h0.w * w0.w;
            a1 += h1.x * w1.x + h1.y * w1.y + h1.z * w1.z + h1.w * w1.w;
            a2 += h2.x * w2.x + h2.y * w2.y + h2.z * w2.z + h2.w * w2.w;
            a3 += h3.x * w3.x + h3.y * w3.y + h3.z * w3.z + h3.w * w3.w;
        }
        float gh = bj + ((a0 + a1) + (a2 + a3));
        float rsum = gv + gh;            // r-gate pre-activation (valid for j<96)
        if (j >= 192)      { bufni[j - 192] = gv; bufnh[j - 192] = gh; }
        else if (j >= 96)  { bufz[j - 96] = rsum; }
        __syncthreads();
        if (j < 96) {
            float rg = 1.f / (1.f + __expf(-rsum));
            float zg = 1.f / (1.f + __expf(-bufz[j]));
            float ng = tanhf(bufni[j] + rg * bufnh[j]);
            hj = (1.f - zg) * ng + zg * hj;
            h_l[j] = hj;
            hout[((size_t)i * T_ + n) * HC + u * 96 + j] = __float2bfloat16(hj);
        }
        gv = gvn;
        __syncthreads();
    }
}

// ---------------------------------------------------------------------------
// Kernel B-fallback: chunked per-direction GRU (used only if ws is small).
// ---------------------------------------------------------------------------
__global__ __launch_bounds__(288, 1) void k_gru_seq(
        const __hip_bfloat16* __restrict__ gi,
        const float* __restrict__ whh,
        const float* __restrict__ bhh,
        __hip_bfloat16* __restrict__ hout,
        int t0, int TC, int u)
{
    const int nl = blockIdx.x;
    const int j = threadIdx.x;           // 0..287
    __shared__ __align__(16) float h_l[96];
    __shared__ float bufz[96], bufni[96], bufnh[96];
    float4 w[24];
    {
        const float4* wr = (const float4*)(whh + (size_t)j * 96);
#pragma unroll
        for (int k = 0; k < 24; ++k) w[k] = wr[k];
    }
    const float bj = bhh[j];
    if (j < 96) h_l[j] = 0.f;
    __syncthreads();
    for (int s = 0; s < 128; ++s) {
        const int i = u ? (127 - s) : s;
        const float gv = (float)gi[((size_t)i * TC + nl) * 288 + j];
        float a0 = 0.f, a1 = 0.f, a2 = 0.f, a3 = 0.f;
        const float4* h4 = (const float4*)(&h_l[0]);
#pragma unroll
        for (int q = 0; q < 6; ++q) {
            float4 h0 = h4[4 * q],     h1 = h4[4 * q + 1];
            float4 h2 = h4[4 * q + 2], h3 = h4[4 * q + 3];
            a0 += h0.x * w[4*q].x + h0.y * w[4*q].y + h0.z * w[4*q].z + h0.w * w[4*q].w;
            a1 += h1.x * w[4*q+1].x + h1.y * w[4*q+1].y + h1.z * w[4*q+1].z + h1.w * w[4*q+1].w;
            a2 += h2.x * w[4*q+2].x + h2.y * w[4*q+2].y + h2.z * w[4*q+2].z + h2.w * w[4*q+2].w;
            a3 += h3.x * w[4*q+3].x + h3.y * w[4*q+3].y + h3.z * w[4*q+3].z + h3.w * w[4*q+3].w;
        }
        float gh = bj + ((a0 + a1) + (a2 + a3));
        if (j >= 192)      { bufni[j - 192] = gv; bufnh[j - 192] = gh; }
        else if (j >= 96)  { bufz[j - 96] = gv + gh; }
        __syncthreads();
        if (j < 96) {
            float rg = 1.f / (1.f + __expf(-(gv + gh)));
            float zg = 1.f / (1.f + __expf(-bufz[j]));
            float ng = tanhf(bufni[j] + rg * bufnh[j]);
            float hn = (1.f - zg) * ng + zg * h_l[j];
            h_l[j] = hn;
            hout[((size_t)i * T_ + (t0 + nl)) * HC + u * 96 + j] = __float2bfloat16(hn);
        }
        __syncthreads();
    }
}

// ---------------------------------------------------------------------------
// Kernel C1: tt = tanh(h @ A1 + b1)    M=102400, K=192, N=50 (pad 64), MFMA
// ---------------------------------------------------------------------------
__global__ __launch_bounds__(256) void k_att1(
        const __hip_bfloat16* __restrict__ h,
        const float* __restrict__ A1,
        const float* __restrict__ b1,
        __hip_bfloat16* __restrict__ tt)
{
    const int m0 = blockIdx.x * 64;      // 1600 blocks
    const int tid = threadIdx.x;
    __shared__ __align__(16) unsigned short At[64 * 200];
    __shared__ __align__(16) unsigned short Bhi[64 * 200];
    __shared__ __align__(16) unsigned short Blo[64 * 200];
    for (int idx = tid; idx < 64 * 96; idx += 256) {
        int r = idx / 96, p = idx - r * 96;
        unsigned int v = *(const unsigned int*)((const unsigned short*)h + ((size_t)(m0 + r) * HC + 2 * p));
        *(unsigned int*)(&At[r * 200 + 2 * p]) = v;
    }
    for (int idx = tid; idx < 64 * 192; idx += 256) {
        int nn = idx / 192, k = idx - nn * 192;
        unsigned short vh = 0, vl = 0;
        if (nn < 50) split_hilo(A1[k * 50 + nn], vh, vl);   // transpose A1 -> B[n][k]
        Bhi[nn * 200 + k] = vh;
        Blo[nn * 200 + k] = vl;
    }
    __syncthreads();
    const int w = tid >> 6, l = tid & 63;
    const int lr = l & 15, quad = l >> 4;
    f32x4 z4 = {0.f, 0.f, 0.f, 0.f};
    f32x4 acc[4];
#pragma unroll
    for (int i = 0; i < 4; ++i) acc[i] = z4;
#pragma unroll
    for (int kk = 0; kk < 6; ++kk) {
        bf16x8 af = *(const bf16x8*)(&At[(w * 16 + lr) * 200 + kk * 32 + quad * 8]);
#pragma unroll
        for (int ns = 0; ns < 4; ++ns) {
            bf16x8 bh = *(const bf16x8*)(&Bhi[(ns * 16 + lr) * 200 + kk * 32 + quad * 8]);
            bf16x8 bl = *(const bf16x8*)(&Blo[(ns * 16 + lr) * 200 + kk * 32 + quad * 8]);
            acc[ns] = __builtin_amdgcn_mfma_f32_16x16x32_bf16(af, bh, acc[ns], 0, 0, 0);
            acc[ns] = __builtin_amdgcn_mfma_f32_16x16x32_bf16(af, bl, acc[ns], 0, 0, 0);
        }
    }
#pragma unroll
    for (int ns = 0; ns < 4; ++ns) {
        int col = ns * 16 + lr;
        if (col < 50) {
            float bias = b1[col];
#pragma unroll
            for (int r2 = 0; r2 < 4; ++r2) {
                int grow = m0 + w * 16 + quad * 4 + r2;
                tt[(size_t)grow * 50 + col] = __float2bfloat16(tanhf(acc[ns][r2] + bias));
            }
        }
    }
}

// ---------------------------------------------------------------------------
// Kernel C2: att = softmax(tt @ A2 + b2, axis=-1)   one row per lane
// ---------------------------------------------------------------------------
__global__ __launch_bounds__(256) void k_att2(
        const __hip_bfloat16* __restrict__ tt,
        const float* __restrict__ A2,
        const float* __restrict__ b2,
        float* __restrict__ att)
{
    __shared__ float A2l[600];
    __shared__ float b2l[12];
    const int tid = threadIdx.x;
    for (int idx = tid; idx < 600; idx += 256) A2l[idx] = A2[idx];
    if (tid < 12) b2l[tid] = b2[tid];
    __syncthreads();
    const int row = blockIdx.x * 256 + tid;    // 400*256 == 102400 exact
    float acc[12];
#pragma unroll
    for (int r = 0; r < 12; ++r) acc[r] = b2l[r];
    const __hip_bfloat16* trow = tt + (size_t)row * 50;
    for (int jj = 0; jj < 50; ++jj) {
        float tv = (float)trow[jj];
#pragma unroll
        for (int r = 0; r < 12; ++r) acc[r] += tv * A2l[jj * 12 + r];
    }
    float mx = acc[0];
#pragma unroll
    for (int r = 1; r < 12; ++r) mx = fmaxf(mx, acc[r]);
    float sm = 0.f;
#pragma unroll
    for (int r = 0; r < 12; ++r) { acc[r] = __expf(acc[r] - mx); sm += acc[r]; }
    float inv = 1.f / sm;
#pragma unroll
    for (int r = 0; r < 12; ++r) att[(size_t)row * 12 + r] = acc[r] * inv;
}

// ---------------------------------------------------------------------------
// Kernel D1: per-batch pooling: m = att^T h, g = att^T att, squash -> v0, nrm
// ---------------------------------------------------------------------------
__global__ __launch_bounds__(256) void k_pool(
        const __hip_bfloat16* __restrict__ h,
        const float* __restrict__ att,
        float* __restrict__ v0g,      // [128][12][192] fp32
        float* __restrict__ norms)
{
    const int b = blockIdx.x;
    const int tid = threadIdx.x;
    __shared__ __align__(16) unsigned short hT[64 * 192];
    __shared__ float attT[64 * 12];
    __shared__ float m_l[12 * 192];
    __shared__ float g_l[144];
    __shared__ float scl[12];

    float macc[12];
#pragma unroll
    for (int r = 0; r < 12; ++r) macc[r] = 0.f;
    float gacc[3] = {0.f, 0.f, 0.f};

    for (int t0 = 0; t0 < T_; t0 += 64) {
        __syncthreads();
        for (int idx = tid; idx < 64 * 96; idx += 256) {
            int rr = idx / 96, p = idx - rr * 96;
            unsigned int v = 0;
            if (t0 + rr < T_)   // zero-pad tail tile (800 = 12*64 + 32)
                v = *(const unsigned int*)((const unsigned short*)h +
                                ((size_t)(b * T_ + t0 + rr) * HC + 2 * p));
            *(unsigned int*)(&hT[rr * 192 + 2 * p]) = v;
        }
        for (int idx = tid; idx < 64 * 12; idx += 256) {
            int rr = idx / 12;
            attT[idx] = (t0 + rr < T_) ? att[(size_t)(b * T_ + t0) * 12 + idx] : 0.f;
        }
        __syncthreads();
        if (tid < 192) {
            for (int t2 = 0; t2 < 64; ++t2) {
                float hv = (float)(*(const __hip_bfloat16*)(&hT[t2 * 192 + tid]));
#pragma unroll
                for (int r = 0; r < 12; ++r) macc[r] += hv * attT[t2 * 12 + r];
            }
        } else {
            int e = tid - 192;
#pragma unroll
            for (int q = 0; q < 3; ++q) {
                int idx = e + 64 * q;
                if (idx < 144) {
                    int rr = idx / 12, ss = idx - rr * 12;
                    float s2 = 0.f;
                    for (int t2 = 0; t2 < 64; ++t2) s2 += attT[t2 * 12 + rr] * attT[t2 * 12 + ss];
                    gacc[q] += s2;
                }
            }
        }
    }
    __syncthreads();
    if (tid < 192) { for (int r = 0; r < 12; ++r) m_l[r * 192 + tid] = macc[r]; }
    else {
        int e = tid - 192;
#pragma unroll
        for (int q = 0; q < 3; ++q) { int idx = e + 64 * q; if (idx < 144) g_l[idx] = gacc[q]; }
    }
    __syncthreads();
    if (tid == 0) {
        float s2 = 0.f;
        for (int idx = 0; idx < 144; ++idx) {
            float v = g_l[idx] - ((idx / 12 == idx % 12) ? 1.f : 0.f);
            s2 += v * v;
        }
        norms[b] = sqrtf(s2);
    }
    if (tid < 12) {
        float n2 = 0.f;
        for (int i = 0; i < 192; ++i) { float v = m_l[tid * 192 + i]; n2 += v * v; }
        scl[tid] = squash_scale(n2);
    }
    __syncthreads();
    if (tid < 192) {
#pragma unroll
        for (int r = 0; r < 12; ++r)
            v0g[((size_t)b * 12 + r) * 192 + tid] = m_l[r * 192 + tid] * scl[r];
    }
}

// ---------------------------------------------------------------------------
// Kernel D2: u_hat GEMM per r: [128 x 192] @ [192 x 800]. Grid (12, 2, 13).
// ---------------------------------------------------------------------------
__global__ __launch_bounds__(256) void k_uhat(
        const float* __restrict__ v0g,
        const float* __restrict__ Wc,
        float* __restrict__ u_hat)    // [128][12][800] fp32
{
    const int r  = blockIdx.x;           // 0..11
    const int m0 = blockIdx.y * 64;      // 0,64
    const int n0 = blockIdx.z * 64;      // 0..768 (tail tile 32 valid)
    const int tid = threadIdx.x;
    __shared__ __align__(16) unsigned short At[64 * 200];
    __shared__ __align__(16) unsigned short Bt[64 * 200];
    for (int idx = tid; idx < 64 * 96; idx += 256) {
        int row = idx / 96, p = idx - row * 96;
        float2 f = *(const float2*)(v0g + ((size_t)(m0 + row) * 12 + r) * 192 + 2 * p);
        *(unsigned int*)(&At[row * 200 + 2 * p]) = pack_bf16x2(f.x, f.y);
    }
    for (int idx = tid; idx < 192 * 64; idx += 256) {
        int k = idx >> 6, nn = idx & 63;
        unsigned short v = 0;
        if (n0 + nn < 800) v = bf16_bits(Wc[((size_t)r * 192 + k) * 800 + n0 + nn]);
        Bt[nn * 200 + k] = v;
    }
    __syncthreads();
    const int w = tid >> 6, l = tid & 63;
    const int lr = l & 15, quad = l >> 4;
    f32x4 z4 = {0.f, 0.f, 0.f, 0.f};
    f32x4 acc[4];
#pragma unroll
    for (int i = 0; i < 4; ++i) acc[i] = z4;
#pragma unroll
    for (int kk = 0; kk < 6; ++kk) {
        bf16x8 af = *(const bf16x8*)(&At[(w * 16 + lr) * 200 + kk * 32 + quad * 8]);
#pragma unroll
        for (int ns = 0; ns < 4; ++ns) {
            bf16x8 bv = *(const bf16x8*)(&Bt[(ns * 16 + lr) * 200 + kk * 32 + quad * 8]);
            acc[ns] = __builtin_amdgcn_mfma_f32_16x16x32_bf16(af, bv, acc[ns], 0, 0, 0);
        }
    }
#pragma unroll
    for (int ns = 0; ns < 4; ++ns) {
        int cco = n0 + ns * 16 + lr;
        if (cco < 800) {
#pragma unroll
            for (int r2 = 0; r2 < 4; ++r2) {
                int brow = m0 + w * 16 + quad * 4 + r2;
                u_hat[((size_t)brow * 12 + r) * 800 + cco] = acc[ns][r2];
            }
        }
    }
}

// ---------------------------------------------------------------------------
// Kernel D3: dynamic routing per batch (u_hat in LDS), 3 iterations, write v.
// ---------------------------------------------------------------------------
__global__ __launch_bounds__(256) void k_route(
        const float* __restrict__ u_hat,
        float* __restrict__ out)
{
    const int b = blockIdx.x;
    const int tid = threadIdx.x;
    __shared__ __align__(16) float u_l[9600];
    __shared__ float blogl[600];
    __shared__ float c_l[600];
    __shared__ float s_l[800];
    __shared__ float v_l[800];
    __shared__ float scl[64];
    {
        const float4* src = (const float4*)(u_hat + (size_t)b * 9600);
        float4* dst = (float4*)u_l;
        for (int e = tid; e < 2400; e += 256) dst[e] = src[e];
    }
    for (int e = tid; e < 600; e += 256) blogl[e] = 0.f;
    __syncthreads();
    for (int it = 0; it < 3; ++it) {
        if (tid < 12) {
            float mx = -1e30f;
            for (int cc = 0; cc < 50; ++cc) mx = fmaxf(mx, blogl[tid * 50 + cc]);
            float sm = 0.f;
            for (int cc = 0; cc < 50; ++cc) {
                float e2 = __expf(blogl[tid * 50 + cc] - mx);
                c_l[tid * 50 + cc] = e2; sm += e2;
            }
            float inv = 1.f / sm;
            for (int cc = 0; cc < 50; ++cc) c_l[tid * 50 + cc] *= inv;
        }
        __syncthreads();
        for (int e = tid; e < 800; e += 256) {
            int cc = e >> 4;
            float sv = 0.f;
#pragma unroll
            for (int r = 0; r < 12; ++r) sv += c_l[r * 50 + cc] * u_l[r * 800 + e];
            s_l[e] = sv;
        }
        __syncthreads();
        for (int cc = tid; cc < 50; cc += 256) {
            float n2 = 0.f;
#pragma unroll
            for (int o = 0; o < 16; ++o) { float v = s_l[cc * 16 + o]; n2 += v * v; }
            scl[cc] = squash_scale(n2);
        }
        __syncthreads();
        for (int e = tid; e < 800; e += 256) v_l[e] = s_l[e] * scl[e >> 4];
        __syncthreads();
        if (it < 2) {
            for (int e = tid; e < 600; e += 256) {
                int cc = e % 50;
                float dd = 0.f;
#pragma unroll
                for (int o = 0; o < 16; ++o) dd += u_l[e * 16 + o] * v_l[cc * 16 + o];
                blogl[e] += dd;
            }
            __syncthreads();
        }
    }
    for (int e = tid; e < 800; e += 256) out[(size_t)b * 800 + e] = v_l[e];
}

// ---------------------------------------------------------------------------
// Kernel E: att_reg = mean(norms)
// ---------------------------------------------------------------------------
__global__ void k_reg(const float* __restrict__ norms, float* __restrict__ out)
{
    const int l = threadIdx.x;           // 64
    float v = norms[l] + norms[l + 64];
#pragma unroll
    for (int off = 32; off; off >>= 1) v += __shfl_down(v, off);
    if (l == 0) out[OUTV] = v * (1.f / 128.f);
}

// ---------------------------------------------------------------------------
extern "C" void kernel_launch(void* const* d_in, const int* in_sizes, int n_in,
                              void* d_out, int out_size, void* d_ws, size_t ws_size,
                              hipStream_t stream) {
    const int*   tokens = (const int*)d_in[0];
    const float* emb    = (const float*)d_in[1];
    const float* wih_f  = (const float*)d_in[2];
    const float* whh_f  = (const float*)d_in[3];
    const float* bih_f  = (const float*)d_in[4];
    const float* bhh_f  = (const float*)d_in[5];
    const float* wih_b  = (const float*)d_in[6];
    const float* whh_b  = (const float*)d_in[7];
    const float* bih_b  = (const float*)d_in[8];
    const float* bhh_b  = (const float*)d_in[9];
    const float* A1     = (const float*)d_in[10];
    const float* b1     = (const float*)d_in[11];
    const float* A2     = (const float*)d_in[12];
    const float* b2     = (const float*)d_in[13];
    const float* Wc     = (const float*)d_in[14];

    const size_t HB = 39321600;                  // hbuf: 102400*192*2 (bf16)
    const size_t GI = 58982400;                  // one direction gi: 128*800*288*2
    char* ws = (char*)d_ws;
    __hip_bfloat16* hbuf = (__hip_bfloat16*)ws;
    float* out = (float*)d_out;

    if (ws_size >= HB + 2 * GI + 11010560) {
        // ---- primary path: both directions resident, single merged GRU ----
        __hip_bfloat16* gi_f = (__hip_bfloat16*)(ws + HB);
        __hip_bfloat16* gi_b = (__hip_bfloat16*)(ws + HB + GI);
        char* tail = ws + HB + 2 * GI;
        __hip_bfloat16* tt   = (__hip_bfloat16*)(ws + HB);   // reuses gi_f after GRU
        float*          att  = (float*)(tail);               //  4,915,200
        float*          nrm  = (float*)(tail + 4915200);     //        512
        float*          v0g  = (float*)(tail + 4915712);     //  1,179,648
        float*          uhat = (float*)(tail + 6095360);     //  4,915,200 -> 11,010,560
        k_gi  <<<dim3(1600, 5), 256, 0, stream>>>(tokens, emb, wih_f, bih_f, gi_f, 0, T_);
        k_gi  <<<dim3(1600, 5), 256, 0, stream>>>(tokens, emb, wih_b, bih_b, gi_b, 0, T_);
        k_gru2<<<dim3(800, 2), 288, 0, stream>>>(gi_f, gi_b, whh_f, whh_b, bhh_f, bhh_b, hbuf);
        k_att1 <<<1600, 256, 0, stream>>>(hbuf, A1, b1, tt);
        k_att2 <<<400, 256, 0, stream>>>(tt, A2, b2, att);
        k_pool <<<128, 256, 0, stream>>>(hbuf, att, v0g, nrm);
        k_uhat <<<dim3(12, 2, 13), 256, 0, stream>>>(v0g, Wc, uhat);
        k_route<<<128, 256, 0, stream>>>(uhat, out);
        k_reg  <<<1, 64, 0, stream>>>(nrm, out);
    } else {
        // ---- fallback: chunked per-direction ----
        char* region2 = ws + HB;
        int TC = (ws_size >= HB + (size_t)128 * 400 * 288 * 2 + 21250560) ? 400 : 200;
        __hip_bfloat16* gi   = (__hip_bfloat16*)region2;
        __hip_bfloat16* tt   = (__hip_bfloat16*)region2;
        float*          att  = (float*)(region2 + 10240000);
        float*          nrm  = (float*)(region2 + 15155200);
        float*          v0g  = (float*)(region2 + 15155712);
        float*          uhat = (float*)(region2 + 16335360);
        for (int u = 0; u < 2; ++u) {
            const float* wih = u ? wih_b : wih_f;
            const float* whh = u ? whh_b : whh_f;
            const float* bih = u ? bih_b : bih_f;
            const float* bhh = u ? bhh_b : bhh_f;
            for (int t0 = 0; t0 < T_; t0 += TC) {
                k_gi <<<dim3(128 * TC / 64, 5), 256, 0, stream>>>(tokens, emb, wih, bih, gi, t0, TC);
                k_gru_seq<<<TC, 288, 0, stream>>>(gi, whh, bhh, hbuf, t0, TC, u);
            }
        }
        k_att1 <<<1600, 256, 0, stream>>>(hbuf, A1, b1, tt);
        k_att2 <<<400, 256, 0, stream>>>(tt, A2, b2, att);
        k_pool <<<128, 256, 0, stream>>>(hbuf, att, v0g, nrm);
        k_uhat <<<dim3(12, 2, 13), 256, 0, stream>>>(v0g, Wc, uhat);
        k_route<<<128, 256, 0, stream>>>(uhat, out);
        k_reg  <<<1, 64, 0, stream>>>(nrm, out);
    }
}

// Round 9
// 960.989 us; speedup vs baseline: 1.4763x; 1.2314x over previous
//
#include <hip/hip_runtime.h>
#include <hip/hip_bf16.h>
#include <math.h>

typedef short bf16x8 __attribute__((ext_vector_type(8)));
typedef _Float16 half8 __attribute__((ext_vector_type(8)));
typedef float f32x4 __attribute__((ext_vector_type(4)));

#define B_   128
#define T_   800
#define E_   100
#define HC   192       // 2H
#define OUTV 102400    // B*C*O

__device__ inline float squash_scale(float n2) {
    return (n2 / (n2 + 1.f)) * rsqrtf(fmaxf(n2, 1e-30f));
}

__device__ inline unsigned short bf16_bits(float x) {
    __hip_bfloat16 h = __float2bfloat16(x);
    return *(unsigned short*)&h;
}

__device__ inline unsigned int pack_bf16x2(float a, float b) {
    return (unsigned int)bf16_bits(a) | ((unsigned int)bf16_bits(b) << 16);
}

__device__ inline void split_hilo(float x, unsigned short& hi, unsigned short& lo) {
    __hip_bfloat16 h = __float2bfloat16(x);
    float hf = __bfloat162float(h);
    hi = *(unsigned short*)&h;
    __hip_bfloat16 l = __float2bfloat16(x - hf);
    lo = *(unsigned short*)&l;
}

__device__ inline float f16u_to_f(unsigned short s) {
    _Float16 h;
    __builtin_memcpy(&h, &s, 2);
    return (float)h;
}

__device__ inline float fast_sigmoid(float x) { return 1.f / (1.f + __expf(-x)); }
__device__ inline float fast_tanh(float x) {
    float e = __expf(2.f * x);
    return 1.f - 2.f / (e + 1.f);
}

// ---------------------------------------------------------------------------
// Kernel A: gi = gather(emb, tokens) @ wih^T + bih for ONE direction, written
// directly into the GRU's lane-packed f16 layout gi3:
//   elem = ((b*100 + t/8)*3 + wv)*768 + lane*24 + (pp*3+g)*4 + reg
//   where (for t: quad=(t&7)>>2, reg=t&3; for col n: g=n/96, j=n%96,
//   tt=j>>4, wv=tt>>1, pp=tt&1, lane=quad*16+(j&15))
// ---------------------------------------------------------------------------
__global__ __launch_bounds__(256) void k_gi(const int* __restrict__ tokens,
        const float* __restrict__ emb,
        const float* __restrict__ wih,
        const float* __restrict__ bih,
        unsigned short* __restrict__ gi3)
{
    const int m0 = blockIdx.x * 64;      // 1600 blocks
    const int n0 = blockIdx.y * 64;      // 0,64,128,192,256
    const int tid = threadIdx.x;
    __shared__ __align__(16) unsigned short At[64 * 136];
    __shared__ __align__(16) unsigned short Bhi[64 * 136];
    __shared__ __align__(16) unsigned short Blo[64 * 136];
    __shared__ int tok[64];
    if (tid < 64) tok[tid] = tokens[m0 + tid];   // rows are b*800+t, tokens[b][t]
    __syncthreads();
    for (int idx = tid; idx < 64 * 64; idx += 256) {
        int r = idx >> 6, p = idx & 63;
        unsigned int v = 0;
        if (p < 50) {
            float2 f = *(const float2*)(emb + (size_t)tok[r] * E_ + 2 * p);
            v = pack_bf16x2(f.x, f.y);
        }
        *(unsigned int*)(&At[r * 136 + 2 * p]) = v;
    }
    for (int idx = tid; idx < 64 * 64; idx += 256) {
        int nn = idx >> 6, p = idx & 63;
        int gc = n0 + nn;
        unsigned int vh = 0, vl = 0;
        if (p < 50 && gc < 288) {
            float2 f = *(const float2*)(wih + (size_t)gc * E_ + 2 * p);
            unsigned short h0, l0, h1, l1;
            split_hilo(f.x, h0, l0);
            split_hilo(f.y, h1, l1);
            vh = (unsigned int)h0 | ((unsigned int)h1 << 16);
            vl = (unsigned int)l0 | ((unsigned int)l1 << 16);
        }
        *(unsigned int*)(&Bhi[nn * 136 + 2 * p]) = vh;
        *(unsigned int*)(&Blo[nn * 136 + 2 * p]) = vl;
    }
    __syncthreads();
    const int w = tid >> 6, l = tid & 63;
    const int lr = l & 15, quad = l >> 4;
    f32x4 z4 = {0.f, 0.f, 0.f, 0.f};
    f32x4 acc[4];
#pragma unroll
    for (int i = 0; i < 4; ++i) acc[i] = z4;
#pragma unroll
    for (int kk = 0; kk < 4; ++kk) {
        bf16x8 af = *(const bf16x8*)(&At[(w * 16 + lr) * 136 + kk * 32 + quad * 8]);
#pragma unroll
        for (int ns = 0; ns < 4; ++ns) {
            bf16x8 bh = *(const bf16x8*)(&Bhi[(ns * 16 + lr) * 136 + kk * 32 + quad * 8]);
            bf16x8 bl = *(const bf16x8*)(&Blo[(ns * 16 + lr) * 136 + kk * 32 + quad * 8]);
            acc[ns] = __builtin_amdgcn_mfma_f32_16x16x32_bf16(af, bh, acc[ns], 0, 0, 0);
            acc[ns] = __builtin_amdgcn_mfma_f32_16x16x32_bf16(af, bl, acc[ns], 0, 0, 0);
        }
    }
#pragma unroll
    for (int ns = 0; ns < 4; ++ns) {
        int gcol = n0 + ns * 16 + lr;
        if (gcol < 288) {
            float bias = bih[gcol];
            int g = (gcol >= 192) ? 2 : (gcol >= 96 ? 1 : 0);
            int j = gcol - g * 96;
            int tt = j >> 4, wv3 = tt >> 1, pp = tt & 1, c16 = j & 15;
#pragma unroll
            for (int r2 = 0; r2 < 4; ++r2) {
                int grow = m0 + w * 16 + quad * 4 + r2;
                int b = grow / 800, t = grow - b * 800;
                int blk = t >> 3, lm = t & 7;
                int lane = ((lm >> 2) << 4) + c16, reg = lm & 3;
                size_t elem = (((size_t)b * 100 + blk) * 3 + wv3) * 768
                              + (size_t)lane * 24 + (pp * 3 + g) * 4 + reg;
                _Float16 hv = (_Float16)(acc[ns][r2] + bias);
                unsigned short bits;
                __builtin_memcpy(&bits, &hv, 2);
                gi3[elem] = bits;
            }
        }
    }
}

// ---------------------------------------------------------------------------
// Kernel B: MFMA GRU. Grid (100, ndir) x 192 threads (3 waves).
// Block owns 8 chains; per step computes [8x96]@[96x288] via f16 MFMA.
// whh in 18 f16 B-fragments (72 VGPRs, loop-invariant MFMA operands);
// h state fp32 in owning lanes' registers; h broadcast f16 in LDS (pad 104);
// gi3 lane-packed, 3x b128 per lane per step, prefetched one step ahead.
// Tile pairing puts (r,z,n) preacts for the same (chain,j) in the same lane.
// No libcalls in the loop (manual exp-based sigmoid/tanh).
// ---------------------------------------------------------------------------
__global__ __launch_bounds__(192, 1) void k_gru3(
        const unsigned short* __restrict__ gi3_f,
        const unsigned short* __restrict__ gi3_b,
        const float* __restrict__ whh_f, const float* __restrict__ whh_b,
        const float* __restrict__ bhh_f, const float* __restrict__ bhh_b,
        __hip_bfloat16* __restrict__ hout, int uoff)
{
    const int blk = blockIdx.x;          // 0..99
    const int u = blockIdx.y + uoff;     // 0 fwd, 1 bwd
    const int tid = threadIdx.x;
    const int wv = tid >> 6, lane = tid & 63;
    const int c16 = lane & 15, quad = lane >> 4;
    const unsigned short* gi3 = u ? gi3_b : gi3_f;
    const float* whh = u ? whh_b : whh_f;
    const float* bhh = u ? bhh_b : bhh_f;

    __shared__ _Float16 h16[16 * 104];   // rows 8..15 stay zero (M pad)

    // --- loop-invariant B fragments + biases ---
    half8 bf[2][3][3];                   // [pair][gate][kchunk]
    float bias[2][3];
#pragma unroll
    for (int pp = 0; pp < 2; ++pp)
#pragma unroll
        for (int g = 0; g < 3; ++g) {
            int n = g * 96 + (2 * wv + pp) * 16 + c16;
            bias[pp][g] = bhh[n];
#pragma unroll
            for (int kc = 0; kc < 3; ++kc) {
                const float* wp = whh + (size_t)n * 96 + kc * 32 + quad * 8;
                half8 hb;
#pragma unroll
                for (int e = 0; e < 8; ++e) hb[e] = (_Float16)wp[e];
                bf[pp][g][kc] = hb;
            }
        }

    for (int idx = tid; idx < 16 * 104; idx += 192) h16[idx] = (_Float16)0.f;
    float hst[2][4];                     // fp32 state, lanes<32 own (pp,reg)
#pragma unroll
    for (int pp = 0; pp < 2; ++pp)
#pragma unroll
        for (int rg = 0; rg < 4; ++rg) hst[pp][rg] = 0.f;
    __syncthreads();

    const int valid = (lane < 32);
    const size_t wvlane = (size_t)wv * 768 + (size_t)lane * 24;

    uint4 cur0, cur1, cur2;
    {
        int i0 = u ? 127 : 0;
        if (valid) {
            const uint4* p = (const uint4*)(gi3 + ((size_t)i0 * 100 + blk) * 2304 + wvlane);
            cur0 = p[0]; cur1 = p[1]; cur2 = p[2];
        }
    }

    for (int s = 0; s < 128; ++s) {
        const int i = u ? (127 - s) : s;
        // A fragments (f16 h broadcast)
        half8 a0 = *(const half8*)(&h16[c16 * 104 + 0  + quad * 8]);
        half8 a1 = *(const half8*)(&h16[c16 * 104 + 32 + quad * 8]);
        half8 a2 = *(const half8*)(&h16[c16 * 104 + 64 + quad * 8]);
        f32x4 acc[2][3];
#pragma unroll
        for (int pp = 0; pp < 2; ++pp)
#pragma unroll
            for (int g = 0; g < 3; ++g) {
                f32x4 c = {0.f, 0.f, 0.f, 0.f};
                c = __builtin_amdgcn_mfma_f32_16x16x32_f16(a0, bf[pp][g][0], c, 0, 0, 0);
                c = __builtin_amdgcn_mfma_f32_16x16x32_f16(a1, bf[pp][g][1], c, 0, 0, 0);
                c = __builtin_amdgcn_mfma_f32_16x16x32_f16(a2, bf[pp][g][2], c, 0, 0, 0);
                acc[pp][g] = c;
            }
        // prefetch next step's gi (h-independent)
        uint4 nx0, nx1, nx2;
        {
            int inx = (s < 127) ? (u ? i - 1 : i + 1) : i;
            if (valid) {
                const uint4* p = (const uint4*)(gi3 + ((size_t)inx * 100 + blk) * 2304 + wvlane);
                nx0 = p[0]; nx1 = p[1]; nx2 = p[2];
            }
        }
        __syncthreads();                 // all A-frag reads done before h16 writes
        if (valid) {
            unsigned int cw[12];
            *(uint4*)(&cw[0]) = cur0; *(uint4*)(&cw[4]) = cur1; *(uint4*)(&cw[8]) = cur2;
#pragma unroll
            for (int pp = 0; pp < 2; ++pp) {
                const int j = (2 * wv + pp) * 16 + c16;
#pragma unroll
                for (int rg = 0; rg < 4; ++rg) {
                    int ir_ = (pp * 3 + 0) * 4 + rg;
                    int iz_ = (pp * 3 + 1) * 4 + rg;
                    int in_ = (pp * 3 + 2) * 4 + rg;
                    float gr = f16u_to_f((unsigned short)((ir_ & 1) ? (cw[ir_ >> 1] >> 16) : (cw[ir_ >> 1] & 0xffff)));
                    float gz = f16u_to_f((unsigned short)((iz_ & 1) ? (cw[iz_ >> 1] >> 16) : (cw[iz_ >> 1] & 0xffff)));
                    float gn = f16u_to_f((unsigned short)((in_ & 1) ? (cw[in_ >> 1] >> 16) : (cw[in_ >> 1] & 0xffff)));
                    float hr = acc[pp][0][rg] + bias[pp][0];
                    float hz = acc[pp][1][rg] + bias[pp][1];
                    float hn = acc[pp][2][rg] + bias[pp][2];
                    float r = fast_sigmoid(gr + hr);
                    float z = fast_sigmoid(gz + hz);
                    float nn = fast_tanh(gn + r * hn);
                    float hp = (1.f - z) * nn + z * hst[pp][rg];
                    hst[pp][rg] = hp;
                    int m = quad * 4 + rg;               // chain-in-block (quad<2)
                    h16[m * 104 + j] = (_Float16)hp;
                    int t = blk * 8 + m;
                    hout[((size_t)i * T_ + t) * HC + u * 96 + j] = __float2bfloat16(hp);
                }
            }
        }
        __syncthreads();                 // h16 writes visible before next reads
        cur0 = nx0; cur1 = nx1; cur2 = nx2;
    }
}

// ---------------------------------------------------------------------------
// Kernel C1: tt = tanh(h @ A1 + b1)    M=102400, K=192, N=50 (pad 64), MFMA
// ---------------------------------------------------------------------------
__global__ __launch_bounds__(256) void k_att1(
        const __hip_bfloat16* __restrict__ h,
        const float* __restrict__ A1,
        const float* __restrict__ b1,
        __hip_bfloat16* __restrict__ tt)
{
    const int m0 = blockIdx.x * 64;      // 1600 blocks
    const int tid = threadIdx.x;
    __shared__ __align__(16) unsigned short At[64 * 200];
    __shared__ __align__(16) unsigned short Bhi[64 * 200];
    __shared__ __align__(16) unsigned short Blo[64 * 200];
    for (int idx = tid; idx < 64 * 96; idx += 256) {
        int r = idx / 96, p = idx - r * 96;
        unsigned int v = *(const unsigned int*)((const unsigned short*)h + ((size_t)(m0 + r) * HC + 2 * p));
        *(unsigned int*)(&At[r * 200 + 2 * p]) = v;
    }
    for (int idx = tid; idx < 64 * 192; idx += 256) {
        int nn = idx / 192, k = idx - nn * 192;
        unsigned short vh = 0, vl = 0;
        if (nn < 50) split_hilo(A1[k * 50 + nn], vh, vl);   // transpose A1 -> B[n][k]
        Bhi[nn * 200 + k] = vh;
        Blo[nn * 200 + k] = vl;
    }
    __syncthreads();
    const int w = tid >> 6, l = tid & 63;
    const int lr = l & 15, quad = l >> 4;
    f32x4 z4 = {0.f, 0.f, 0.f, 0.f};
    f32x4 acc[4];
#pragma unroll
    for (int i = 0; i < 4; ++i) acc[i] = z4;
#pragma unroll
    for (int kk = 0; kk < 6; ++kk) {
        bf16x8 af = *(const bf16x8*)(&At[(w * 16 + lr) * 200 + kk * 32 + quad * 8]);
#pragma unroll
        for (int ns = 0; ns < 4; ++ns) {
            bf16x8 bh = *(const bf16x8*)(&Bhi[(ns * 16 + lr) * 200 + kk * 32 + quad * 8]);
            bf16x8 bl = *(const bf16x8*)(&Blo[(ns * 16 + lr) * 200 + kk * 32 + quad * 8]);
            acc[ns] = __builtin_amdgcn_mfma_f32_16x16x32_bf16(af, bh, acc[ns], 0, 0, 0);
            acc[ns] = __builtin_amdgcn_mfma_f32_16x16x32_bf16(af, bl, acc[ns], 0, 0, 0);
        }
    }
#pragma unroll
    for (int ns = 0; ns < 4; ++ns) {
        int col = ns * 16 + lr;
        if (col < 50) {
            float bias = b1[col];
#pragma unroll
            for (int r2 = 0; r2 < 4; ++r2) {
                int grow = m0 + w * 16 + quad * 4 + r2;
                tt[(size_t)grow * 50 + col] = __float2bfloat16(fast_tanh(acc[ns][r2] + bias));
            }
        }
    }
}

// ---------------------------------------------------------------------------
// Kernel C2: att = softmax(tt @ A2 + b2, axis=-1)   one row per lane
// ---------------------------------------------------------------------------
__global__ __launch_bounds__(256) void k_att2(
        const __hip_bfloat16* __restrict__ tt,
        const float* __restrict__ A2,
        const float* __restrict__ b2,
        float* __restrict__ att)
{
    __shared__ float A2l[600];
    __shared__ float b2l[12];
    const int tid = threadIdx.x;
    for (int idx = tid; idx < 600; idx += 256) A2l[idx] = A2[idx];
    if (tid < 12) b2l[tid] = b2[tid];
    __syncthreads();
    const int row = blockIdx.x * 256 + tid;    // 400*256 == 102400 exact
    float acc[12];
#pragma unroll
    for (int r = 0; r < 12; ++r) acc[r] = b2l[r];
    const __hip_bfloat16* trow = tt + (size_t)row * 50;
    for (int jj = 0; jj < 50; ++jj) {
        float tv = (float)trow[jj];
#pragma unroll
        for (int r = 0; r < 12; ++r) acc[r] += tv * A2l[jj * 12 + r];
    }
    float mx = acc[0];
#pragma unroll
    for (int r = 1; r < 12; ++r) mx = fmaxf(mx, acc[r]);
    float sm = 0.f;
#pragma unroll
    for (int r = 0; r < 12; ++r) { acc[r] = __expf(acc[r] - mx); sm += acc[r]; }
    float inv = 1.f / sm;
#pragma unroll
    for (int r = 0; r < 12; ++r) att[(size_t)row * 12 + r] = acc[r] * inv;
}

// ---------------------------------------------------------------------------
// Kernel D1: per-batch pooling: m = att^T h, g = att^T att, squash -> v0, nrm
// ---------------------------------------------------------------------------
__global__ __launch_bounds__(256) void k_pool(
        const __hip_bfloat16* __restrict__ h,
        const float* __restrict__ att,
        float* __restrict__ v0g,      // [128][12][192] fp32
        float* __restrict__ norms)
{
    const int b = blockIdx.x;
    const int tid = threadIdx.x;
    __shared__ __align__(16) unsigned short hT[64 * 192];
    __shared__ float attT[64 * 12];
    __shared__ float m_l[12 * 192];
    __shared__ float g_l[144];
    __shared__ float scl[12];

    float macc[12];
#pragma unroll
    for (int r = 0; r < 12; ++r) macc[r] = 0.f;
    float gacc[3] = {0.f, 0.f, 0.f};

    for (int t0 = 0; t0 < T_; t0 += 64) {
        __syncthreads();
        for (int idx = tid; idx < 64 * 96; idx += 256) {
            int rr = idx / 96, p = idx - rr * 96;
            unsigned int v = 0;
            if (t0 + rr < T_)   // zero-pad tail tile (800 = 12*64 + 32)
                v = *(const unsigned int*)((const unsigned short*)h +
                                ((size_t)(b * T_ + t0 + rr) * HC + 2 * p));
            *(unsigned int*)(&hT[rr * 192 + 2 * p]) = v;
        }
        for (int idx = tid; idx < 64 * 12; idx += 256) {
            int rr = idx / 12;
            attT[idx] = (t0 + rr < T_) ? att[(size_t)(b * T_ + t0) * 12 + idx] : 0.f;
        }
        __syncthreads();
        if (tid < 192) {
            for (int t2 = 0; t2 < 64; ++t2) {
                float hv = (float)(*(const __hip_bfloat16*)(&hT[t2 * 192 + tid]));
#pragma unroll
                for (int r = 0; r < 12; ++r) macc[r] += hv * attT[t2 * 12 + r];
            }
        } else {
            int e = tid - 192;
#pragma unroll
            for (int q = 0; q < 3; ++q) {
                int idx = e + 64 * q;
                if (idx < 144) {
                    int rr = idx / 12, ss = idx - rr * 12;
                    float s2 = 0.f;
                    for (int t2 = 0; t2 < 64; ++t2) s2 += attT[t2 * 12 + rr] * attT[t2 * 12 + ss];
                    gacc[q] += s2;
                }
            }
        }
    }
    __syncthreads();
    if (tid < 192) { for (int r = 0; r < 12; ++r) m_l[r * 192 + tid] = macc[r]; }
    else {
        int e = tid - 192;
#pragma unroll
        for (int q = 0; q < 3; ++q) { int idx = e + 64 * q; if (idx < 144) g_l[idx] = gacc[q]; }
    }
    __syncthreads();
    if (tid == 0) {
        float s2 = 0.f;
        for (int idx = 0; idx < 144; ++idx) {
            float v = g_l[idx] - ((idx / 12 == idx % 12) ? 1.f : 0.f);
            s2 += v * v;
        }
        norms[b] = sqrtf(s2);
    }
    if (tid < 12) {
        float n2 = 0.f;
        for (int i = 0; i < 192; ++i) { float v = m_l[tid * 192 + i]; n2 += v * v; }
        scl[tid] = squash_scale(n2);
    }
    __syncthreads();
    if (tid < 192) {
#pragma unroll
        for (int r = 0; r < 12; ++r)
            v0g[((size_t)b * 12 + r) * 192 + tid] = m_l[r * 192 + tid] * scl[r];
    }
}

// ---------------------------------------------------------------------------
// Kernel D2: u_hat GEMM per r: [128 x 192] @ [192 x 800]. Grid (12, 2, 13).
// ---------------------------------------------------------------------------
__global__ __launch_bounds__(256) void k_uhat(
        const float* __restrict__ v0g,
        const float* __restrict__ Wc,
        float* __restrict__ u_hat)    // [128][12][800] fp32
{
    const int r  = blockIdx.x;           // 0..11
    const int m0 = blockIdx.y * 64;      // 0,64
    const int n0 = blockIdx.z * 64;      // 0..768 (tail tile 32 valid)
    const int tid = threadIdx.x;
    __shared__ __align__(16) unsigned short At[64 * 200];
    __shared__ __align__(16) unsigned short Bt[64 * 200];
    for (int idx = tid; idx < 64 * 96; idx += 256) {
        int row = idx / 96, p = idx - row * 96;
        float2 f = *(const float2*)(v0g + ((size_t)(m0 + row) * 12 + r) * 192 + 2 * p);
        *(unsigned int*)(&At[row * 200 + 2 * p]) = pack_bf16x2(f.x, f.y);
    }
    for (int idx = tid; idx < 192 * 64; idx += 256) {
        int k = idx >> 6, nn = idx & 63;
        unsigned short v = 0;
        if (n0 + nn < 800) v = bf16_bits(Wc[((size_t)r * 192 + k) * 800 + n0 + nn]);
        Bt[nn * 200 + k] = v;
    }
    __syncthreads();
    const int w = tid >> 6, l = tid & 63;
    const int lr = l & 15, quad = l >> 4;
    f32x4 z4 = {0.f, 0.f, 0.f, 0.f};
    f32x4 acc[4];
#pragma unroll
    for (int i = 0; i < 4; ++i) acc[i] = z4;
#pragma unroll
    for (int kk = 0; kk < 6; ++kk) {
        bf16x8 af = *(const bf16x8*)(&At[(w * 16 + lr) * 200 + kk * 32 + quad * 8]);
#pragma unroll
        for (int ns = 0; ns < 4; ++ns) {
            bf16x8 bv = *(const bf16x8*)(&Bt[(ns * 16 + lr) * 200 + kk * 32 + quad * 8]);
            acc[ns] = __builtin_amdgcn_mfma_f32_16x16x32_bf16(af, bv, acc[ns], 0, 0, 0);
        }
    }
#pragma unroll
    for (int ns = 0; ns < 4; ++ns) {
        int cco = n0 + ns * 16 + lr;
        if (cco < 800) {
#pragma unroll
            for (int r2 = 0; r2 < 4; ++r2) {
                int brow = m0 + w * 16 + quad * 4 + r2;
                u_hat[((size_t)brow * 12 + r) * 800 + cco] = acc[ns][r2];
            }
        }
    }
}

// ---------------------------------------------------------------------------
// Kernel D3: dynamic routing per batch (u_hat in LDS), 3 iterations, write v.
// ---------------------------------------------------------------------------
__global__ __launch_bounds__(256) void k_route(
        const float* __restrict__ u_hat,
        float* __restrict__ out)
{
    const int b = blockIdx.x;
    const int tid = threadIdx.x;
    __shared__ __align__(16) float u_l[9600];
    __shared__ float blogl[600];
    __shared__ float c_l[600];
    __shared__ float s_l[800];
    __shared__ float v_l[800];
    __shared__ float scl[64];
    {
        const float4* src = (const float4*)(u_hat + (size_t)b * 9600);
        float4* dst = (float4*)u_l;
        for (int e = tid; e < 2400; e += 256) dst[e] = src[e];
    }
    for (int e = tid; e < 600; e += 256) blogl[e] = 0.f;
    __syncthreads();
    for (int it = 0; it < 3; ++it) {
        if (tid < 12) {
            float mx = -1e30f;
            for (int cc = 0; cc < 50; ++cc) mx = fmaxf(mx, blogl[tid * 50 + cc]);
            float sm = 0.f;
            for (int cc = 0; cc < 50; ++cc) {
                float e2 = __expf(blogl[tid * 50 + cc] - mx);
                c_l[tid * 50 + cc] = e2; sm += e2;
            }
            float inv = 1.f / sm;
            for (int cc = 0; cc < 50; ++cc) c_l[tid * 50 + cc] *= inv;
        }
        __syncthreads();
        for (int e = tid; e < 800; e += 256) {
            int cc = e >> 4;
            float sv = 0.f;
#pragma unroll
            for (int r = 0; r < 12; ++r) sv += c_l[r * 50 + cc] * u_l[r * 800 + e];
            s_l[e] = sv;
        }
        __syncthreads();
        for (int cc = tid; cc < 50; cc += 256) {
            float n2 = 0.f;
#pragma unroll
            for (int o = 0; o < 16; ++o) { float v = s_l[cc * 16 + o]; n2 += v * v; }
            scl[cc] = squash_scale(n2);
        }
        __syncthreads();
        for (int e = tid; e < 800; e += 256) v_l[e] = s_l[e] * scl[e >> 4];
        __syncthreads();
        if (it < 2) {
            for (int e = tid; e < 600; e += 256) {
                int cc = e % 50;
                float dd = 0.f;
#pragma unroll
                for (int o = 0; o < 16; ++o) dd += u_l[e * 16 + o] * v_l[cc * 16 + o];
                blogl[e] += dd;
            }
            __syncthreads();
        }
    }
    for (int e = tid; e < 800; e += 256) out[(size_t)b * 800 + e] = v_l[e];
}

// ---------------------------------------------------------------------------
// Kernel E: att_reg = mean(norms)
// ---------------------------------------------------------------------------
__global__ void k_reg(const float* __restrict__ norms, float* __restrict__ out)
{
    const int l = threadIdx.x;           // 64
    float v = norms[l] + norms[l + 64];
#pragma unroll
    for (int off = 32; off; off >>= 1) v += __shfl_down(v, off);
    if (l == 0) out[OUTV] = v * (1.f / 128.f);
}

// ---------------------------------------------------------------------------
extern "C" void kernel_launch(void* const* d_in, const int* in_sizes, int n_in,
                              void* d_out, int out_size, void* d_ws, size_t ws_size,
                              hipStream_t stream) {
    const int*   tokens = (const int*)d_in[0];
    const float* emb    = (const float*)d_in[1];
    const float* wih_f  = (const float*)d_in[2];
    const float* whh_f  = (const float*)d_in[3];
    const float* bih_f  = (const float*)d_in[4];
    const float* bhh_f  = (const float*)d_in[5];
    const float* wih_b  = (const float*)d_in[6];
    const float* whh_b  = (const float*)d_in[7];
    const float* bih_b  = (const float*)d_in[8];
    const float* bhh_b  = (const float*)d_in[9];
    const float* A1     = (const float*)d_in[10];
    const float* b1     = (const float*)d_in[11];
    const float* A2     = (const float*)d_in[12];
    const float* b2     = (const float*)d_in[13];
    const float* Wc     = (const float*)d_in[14];

    const size_t HB = 39321600;                  // hbuf: 102400*192*2 (bf16)
    const size_t GI = 58982400;                  // gi3 one dir: 128*100*2304*2
    const size_t TAIL = 11010560;
    char* ws = (char*)d_ws;
    __hip_bfloat16* hbuf = (__hip_bfloat16*)ws;
    float* out = (float*)d_out;

    if (ws_size >= HB + 2 * GI + TAIL) {
        // ---- primary: both directions resident, single merged GRU ----
        unsigned short* gi_f = (unsigned short*)(ws + HB);
        unsigned short* gi_b = (unsigned short*)(ws + HB + GI);
        char* tail = ws + HB + 2 * GI;
        __hip_bfloat16* tt   = (__hip_bfloat16*)(ws + HB);   // reuses gi_f after GRU
        float*          att  = (float*)(tail);
        float*          nrm  = (float*)(tail + 4915200);
        float*          v0g  = (float*)(tail + 4915712);
        float*          uhat = (float*)(tail + 6095360);
        k_gi  <<<dim3(1600, 5), 256, 0, stream>>>(tokens, emb, wih_f, bih_f, gi_f);
        k_gi  <<<dim3(1600, 5), 256, 0, stream>>>(tokens, emb, wih_b, bih_b, gi_b);
        k_gru3<<<dim3(100, 2), 192, 0, stream>>>(gi_f, gi_b, whh_f, whh_b, bhh_f, bhh_b, hbuf, 0);
        k_att1 <<<1600, 256, 0, stream>>>(hbuf, A1, b1, tt);
        k_att2 <<<400, 256, 0, stream>>>(tt, A2, b2, att);
        k_pool <<<128, 256, 0, stream>>>(hbuf, att, v0g, nrm);
        k_uhat <<<dim3(12, 2, 13), 256, 0, stream>>>(v0g, Wc, uhat);
        k_route<<<128, 256, 0, stream>>>(uhat, out);
        k_reg  <<<1, 64, 0, stream>>>(nrm, out);
    } else {
        // ---- compact: one gi3 buffer, directions sequential ----
        unsigned short* gi1 = (unsigned short*)(ws + HB);
        char* tail = ws + HB + GI;
        __hip_bfloat16* tt   = (__hip_bfloat16*)(ws + HB);
        float*          att  = (float*)(tail);
        float*          nrm  = (float*)(tail + 4915200);
        float*          v0g  = (float*)(tail + 4915712);
        float*          uhat = (float*)(tail + 6095360);
        k_gi  <<<dim3(1600, 5), 256, 0, stream>>>(tokens, emb, wih_f, bih_f, gi1);
        k_gru3<<<dim3(100, 1), 192, 0, stream>>>(gi1, gi1, whh_f, whh_b, bhh_f, bhh_b, hbuf, 0);
        k_gi  <<<dim3(1600, 5), 256, 0, stream>>>(tokens, emb, wih_b, bih_b, gi1);
        k_gru3<<<dim3(100, 1), 192, 0, stream>>>(gi1, gi1, whh_f, whh_b, bhh_f, bhh_b, hbuf, 1);
        k_att1 <<<1600, 256, 0, stream>>>(hbuf, A1, b1, tt);
        k_att2 <<<400, 256, 0, stream>>>(tt, A2, b2, att);
        k_pool <<<128, 256, 0, stream>>>(hbuf, att, v0g, nrm);
        k_uhat <<<dim3(12, 2, 13), 256, 0, stream>>>(v0g, Wc, uhat);
        k_route<<<128, 256, 0, stream>>>(uhat, out);
        k_reg  <<<1, 64, 0, stream>>>(nrm, out);
    }
}

// Round 10
// 880.854 us; speedup vs baseline: 1.6106x; 1.0910x over previous
//
#include <hip/hip_runtime.h>
#include <hip/hip_bf16.h>
#include <math.h>

typedef short bf16x8 __attribute__((ext_vector_type(8)));
typedef _Float16 half8 __attribute__((ext_vector_type(8)));
typedef float f32x4 __attribute__((ext_vector_type(4)));

#define B_   128
#define T_   800
#define E_   100
#define HC   192       // 2H
#define OUTV 102400    // B*C*O

__device__ inline float squash_scale(float n2) {
    return (n2 / (n2 + 1.f)) * rsqrtf(fmaxf(n2, 1e-30f));
}

__device__ inline unsigned short bf16_bits(float x) {
    __hip_bfloat16 h = __float2bfloat16(x);
    return *(unsigned short*)&h;
}

__device__ inline unsigned int pack_bf16x2(float a, float b) {
    return (unsigned int)bf16_bits(a) | ((unsigned int)bf16_bits(b) << 16);
}

__device__ inline void split_hilo(float x, unsigned short& hi, unsigned short& lo) {
    __hip_bfloat16 h = __float2bfloat16(x);
    float hf = __bfloat162float(h);
    hi = *(unsigned short*)&h;
    __hip_bfloat16 l = __float2bfloat16(x - hf);
    lo = *(unsigned short*)&l;
}

__device__ inline float f16u_to_f(unsigned short s) {
    _Float16 h;
    __builtin_memcpy(&h, &s, 2);
    return (float)h;
}

__device__ inline unsigned short f16_bits(float x) {
    _Float16 h = (_Float16)x;
    unsigned short b;
    __builtin_memcpy(&b, &h, 2);
    return b;
}

__device__ inline float fast_sigmoid(float x) { return 1.f / (1.f + __expf(-x)); }
__device__ inline float fast_tanh(float x) {
    float e = __expf(2.f * x);
    return 1.f - 2.f / (e + 1.f);
}

// ---------------------------------------------------------------------------
// Kernel A (v2): gi for both directions, one block per 64-row m-tile.
// Computes all 5 n-tiles per direction, stages the C tile in LDS in the
// exact gi3 group layout (8 contiguous groups per m-tile), then writes the
// 36,864-B region with dense coalesced uint4 stores. Kills the 3x HBM
// partial-line write amplification of the scattered f16 stores (round-9
// counters: WRITE 174 MB vs 59 MB payload).
//   gi3 elem = (grow/8)*2304 + wv*768 + lane*24 + (pp*3+g)*4 + reg
//   grow-local: group_local = row>>3, lane = ((quad&1)<<4)+lr, reg = r2
// ---------------------------------------------------------------------------
__global__ __launch_bounds__(256) void k_gi2(const int* __restrict__ tokens,
        const float* __restrict__ emb,
        const float* __restrict__ wih0, const float* __restrict__ wih1,
        const float* __restrict__ bih0, const float* __restrict__ bih1,
        unsigned short* __restrict__ g3_0, unsigned short* __restrict__ g3_1,
        int uoff, int ndir)
{
    const int m0 = blockIdx.x * 64;      // 1600 blocks
    const int tid = threadIdx.x;
    __shared__ __align__(16) unsigned short At[64 * 136];
    __shared__ __align__(16) unsigned short Bhi[64 * 136];
    __shared__ __align__(16) unsigned short Blo[64 * 136];
    __shared__ __align__(16) unsigned short outb[8 * 2304];   // 36,864 B
    __shared__ int tok[64];
    if (tid < 64) tok[tid] = tokens[m0 + tid];
    __syncthreads();
    // stage A tile once (emb gather, bf16 single plane)
    for (int idx = tid; idx < 64 * 64; idx += 256) {
        int r = idx >> 6, p = idx & 63;
        unsigned int v = 0;
        if (p < 50) {
            float2 f = *(const float2*)(emb + (size_t)tok[r] * E_ + 2 * p);
            v = pack_bf16x2(f.x, f.y);
        }
        *(unsigned int*)(&At[r * 136 + 2 * p]) = v;
    }
    const int w = tid >> 6, l = tid & 63;
    const int lr = l & 15, quad = l >> 4;
    const int group_local = w * 2 + (quad >> 1);
    const int lane_g = ((quad & 1) << 4) + lr;

    for (int uu = uoff; uu < uoff + ndir; ++uu) {
        const float* wih = uu ? wih1 : wih0;
        const float* bih = uu ? bih1 : bih0;
        unsigned short* gi3 = uu ? g3_1 : g3_0;
        for (int nt = 0; nt < 5; ++nt) {
            const int n0 = nt * 64;
            __syncthreads();             // prev B reads + prev outb copy done
            for (int idx = tid; idx < 64 * 64; idx += 256) {
                int nn = idx >> 6, p = idx & 63;
                int gc = n0 + nn;
                unsigned int vh = 0, vl = 0;
                if (p < 50 && gc < 288) {
                    float2 f = *(const float2*)(wih + (size_t)gc * E_ + 2 * p);
                    unsigned short h0, l0, h1, l1;
                    split_hilo(f.x, h0, l0);
                    split_hilo(f.y, h1, l1);
                    vh = (unsigned int)h0 | ((unsigned int)h1 << 16);
                    vl = (unsigned int)l0 | ((unsigned int)l1 << 16);
                }
                *(unsigned int*)(&Bhi[nn * 136 + 2 * p]) = vh;
                *(unsigned int*)(&Blo[nn * 136 + 2 * p]) = vl;
            }
            __syncthreads();
            f32x4 z4 = {0.f, 0.f, 0.f, 0.f};
            f32x4 acc[4];
#pragma unroll
            for (int i = 0; i < 4; ++i) acc[i] = z4;
#pragma unroll
            for (int kk = 0; kk < 4; ++kk) {
                bf16x8 af = *(const bf16x8*)(&At[(w * 16 + lr) * 136 + kk * 32 + quad * 8]);
#pragma unroll
                for (int ns = 0; ns < 4; ++ns) {
                    bf16x8 bh = *(const bf16x8*)(&Bhi[(ns * 16 + lr) * 136 + kk * 32 + quad * 8]);
                    bf16x8 bl = *(const bf16x8*)(&Blo[(ns * 16 + lr) * 136 + kk * 32 + quad * 8]);
                    acc[ns] = __builtin_amdgcn_mfma_f32_16x16x32_bf16(af, bh, acc[ns], 0, 0, 0);
                    acc[ns] = __builtin_amdgcn_mfma_f32_16x16x32_bf16(af, bl, acc[ns], 0, 0, 0);
                }
            }
            // stage C fragments into outb (gi3 layout); 4 r2 are contiguous
#pragma unroll
            for (int ns = 0; ns < 4; ++ns) {
                int gcol = n0 + ns * 16 + lr;     // c16 == lr
                if (gcol < 288) {
                    float bias = bih[gcol];
                    int g = (gcol >= 192) ? 2 : (gcol >= 96 ? 1 : 0);
                    int j = gcol - g * 96;
                    int tt = j >> 4, wv3 = tt >> 1, pp = tt & 1;
                    unsigned short* dst = &outb[group_local * 2304 + wv3 * 768
                                                + lane_g * 24 + (pp * 3 + g) * 4];
                    unsigned int w0 = (unsigned int)f16_bits(acc[ns][0] + bias)
                                    | ((unsigned int)f16_bits(acc[ns][1] + bias) << 16);
                    unsigned int w1 = (unsigned int)f16_bits(acc[ns][2] + bias)
                                    | ((unsigned int)f16_bits(acc[ns][3] + bias) << 16);
                    *(unsigned int*)(dst) = w0;
                    *(unsigned int*)(dst + 2) = w1;
                }
            }
        }
        __syncthreads();                 // outb complete
        // dense coalesced copy: 36,864 B -> gi3 region of this m-tile
        const uint4* src = (const uint4*)outb;
        uint4* dst = (uint4*)(gi3 + (size_t)(m0 >> 3) * 2304);
        for (int e = tid; e < 2304; e += 256) dst[e] = src[e];
    }
}

// ---------------------------------------------------------------------------
// Kernel B: MFMA GRU (round-9 verified). Grid (100, ndir) x 192 threads.
// ---------------------------------------------------------------------------
__global__ __launch_bounds__(192, 1) void k_gru3(
        const unsigned short* __restrict__ gi3_f,
        const unsigned short* __restrict__ gi3_b,
        const float* __restrict__ whh_f, const float* __restrict__ whh_b,
        const float* __restrict__ bhh_f, const float* __restrict__ bhh_b,
        __hip_bfloat16* __restrict__ hout, int uoff)
{
    const int blk = blockIdx.x;          // 0..99
    const int u = blockIdx.y + uoff;     // 0 fwd, 1 bwd
    const int tid = threadIdx.x;
    const int wv = tid >> 6, lane = tid & 63;
    const int c16 = lane & 15, quad = lane >> 4;
    const unsigned short* gi3 = u ? gi3_b : gi3_f;
    const float* whh = u ? whh_b : whh_f;
    const float* bhh = u ? bhh_b : bhh_f;

    __shared__ _Float16 h16[16 * 104];   // rows 8..15 stay zero (M pad)

    half8 bf[2][3][3];                   // [pair][gate][kchunk]
    float bias[2][3];
#pragma unroll
    for (int pp = 0; pp < 2; ++pp)
#pragma unroll
        for (int g = 0; g < 3; ++g) {
            int n = g * 96 + (2 * wv + pp) * 16 + c16;
            bias[pp][g] = bhh[n];
#pragma unroll
            for (int kc = 0; kc < 3; ++kc) {
                const float* wp = whh + (size_t)n * 96 + kc * 32 + quad * 8;
                half8 hb;
#pragma unroll
                for (int e = 0; e < 8; ++e) hb[e] = (_Float16)wp[e];
                bf[pp][g][kc] = hb;
            }
        }

    for (int idx = tid; idx < 16 * 104; idx += 192) h16[idx] = (_Float16)0.f;
    float hst[2][4];
#pragma unroll
    for (int pp = 0; pp < 2; ++pp)
#pragma unroll
        for (int rg = 0; rg < 4; ++rg) hst[pp][rg] = 0.f;
    __syncthreads();

    const int valid = (lane < 32);
    const size_t wvlane = (size_t)wv * 768 + (size_t)lane * 24;

    uint4 cur0, cur1, cur2;
    {
        int i0 = u ? 127 : 0;
        if (valid) {
            const uint4* p = (const uint4*)(gi3 + ((size_t)i0 * 100 + blk) * 2304 + wvlane);
            cur0 = p[0]; cur1 = p[1]; cur2 = p[2];
        }
    }

    for (int s = 0; s < 128; ++s) {
        const int i = u ? (127 - s) : s;
        half8 a0 = *(const half8*)(&h16[c16 * 104 + 0  + quad * 8]);
        half8 a1 = *(const half8*)(&h16[c16 * 104 + 32 + quad * 8]);
        half8 a2 = *(const half8*)(&h16[c16 * 104 + 64 + quad * 8]);
        f32x4 acc[2][3];
#pragma unroll
        for (int pp = 0; pp < 2; ++pp)
#pragma unroll
            for (int g = 0; g < 3; ++g) {
                f32x4 c = {0.f, 0.f, 0.f, 0.f};
                c = __builtin_amdgcn_mfma_f32_16x16x32_f16(a0, bf[pp][g][0], c, 0, 0, 0);
                c = __builtin_amdgcn_mfma_f32_16x16x32_f16(a1, bf[pp][g][1], c, 0, 0, 0);
                c = __builtin_amdgcn_mfma_f32_16x16x32_f16(a2, bf[pp][g][2], c, 0, 0, 0);
                acc[pp][g] = c;
            }
        uint4 nx0, nx1, nx2;
        {
            int inx = (s < 127) ? (u ? i - 1 : i + 1) : i;
            if (valid) {
                const uint4* p = (const uint4*)(gi3 + ((size_t)inx * 100 + blk) * 2304 + wvlane);
                nx0 = p[0]; nx1 = p[1]; nx2 = p[2];
            }
        }
        __syncthreads();
        if (valid) {
            unsigned int cw[12];
            *(uint4*)(&cw[0]) = cur0; *(uint4*)(&cw[4]) = cur1; *(uint4*)(&cw[8]) = cur2;
#pragma unroll
            for (int pp = 0; pp < 2; ++pp) {
                const int j = (2 * wv + pp) * 16 + c16;
#pragma unroll
                for (int rg = 0; rg < 4; ++rg) {
                    int ir_ = (pp * 3 + 0) * 4 + rg;
                    int iz_ = (pp * 3 + 1) * 4 + rg;
                    int in_ = (pp * 3 + 2) * 4 + rg;
                    float gr = f16u_to_f((unsigned short)((ir_ & 1) ? (cw[ir_ >> 1] >> 16) : (cw[ir_ >> 1] & 0xffff)));
                    float gz = f16u_to_f((unsigned short)((iz_ & 1) ? (cw[iz_ >> 1] >> 16) : (cw[iz_ >> 1] & 0xffff)));
                    float gn = f16u_to_f((unsigned short)((in_ & 1) ? (cw[in_ >> 1] >> 16) : (cw[in_ >> 1] & 0xffff)));
                    float hr = acc[pp][0][rg] + bias[pp][0];
                    float hz = acc[pp][1][rg] + bias[pp][1];
                    float hn = acc[pp][2][rg] + bias[pp][2];
                    float r = fast_sigmoid(gr + hr);
                    float z = fast_sigmoid(gz + hz);
                    float nn = fast_tanh(gn + r * hn);
                    float hp = (1.f - z) * nn + z * hst[pp][rg];
                    hst[pp][rg] = hp;
                    int m = quad * 4 + rg;
                    h16[m * 104 + j] = (_Float16)hp;
                    int t = blk * 8 + m;
                    hout[((size_t)i * T_ + t) * HC + u * 96 + j] = __float2bfloat16(hp);
                }
            }
        }
        __syncthreads();
        cur0 = nx0; cur1 = nx1; cur2 = nx2;
    }
}

// ---------------------------------------------------------------------------
// Kernel C1: tt = tanh(h @ A1 + b1)    M=102400, K=192, N=50 (pad 64), MFMA
// ---------------------------------------------------------------------------
__global__ __launch_bounds__(256) void k_att1(
        const __hip_bfloat16* __restrict__ h,
        const float* __restrict__ A1,
        const float* __restrict__ b1,
        __hip_bfloat16* __restrict__ tt)
{
    const int m0 = blockIdx.x * 64;      // 1600 blocks
    const int tid = threadIdx.x;
    __shared__ __align__(16) unsigned short At[64 * 200];
    __shared__ __align__(16) unsigned short Bhi[64 * 200];
    __shared__ __align__(16) unsigned short Blo[64 * 200];
    for (int idx = tid; idx < 64 * 96; idx += 256) {
        int r = idx / 96, p = idx - r * 96;
        unsigned int v = *(const unsigned int*)((const unsigned short*)h + ((size_t)(m0 + r) * HC + 2 * p));
        *(unsigned int*)(&At[r * 200 + 2 * p]) = v;
    }
    for (int idx = tid; idx < 64 * 192; idx += 256) {
        int nn = idx / 192, k = idx - nn * 192;
        unsigned short vh = 0, vl = 0;
        if (nn < 50) split_hilo(A1[k * 50 + nn], vh, vl);   // transpose A1 -> B[n][k]
        Bhi[nn * 200 + k] = vh;
        Blo[nn * 200 + k] = vl;
    }
    __syncthreads();
    const int w = tid >> 6, l = tid & 63;
    const int lr = l & 15, quad = l >> 4;
    f32x4 z4 = {0.f, 0.f, 0.f, 0.f};
    f32x4 acc[4];
#pragma unroll
    for (int i = 0; i < 4; ++i) acc[i] = z4;
#pragma unroll
    for (int kk = 0; kk < 6; ++kk) {
        bf16x8 af = *(const bf16x8*)(&At[(w * 16 + lr) * 200 + kk * 32 + quad * 8]);
#pragma unroll
        for (int ns = 0; ns < 4; ++ns) {
            bf16x8 bh = *(const bf16x8*)(&Bhi[(ns * 16 + lr) * 200 + kk * 32 + quad * 8]);
            bf16x8 bl = *(const bf16x8*)(&Blo[(ns * 16 + lr) * 200 + kk * 32 + quad * 8]);
            acc[ns] = __builtin_amdgcn_mfma_f32_16x16x32_bf16(af, bh, acc[ns], 0, 0, 0);
            acc[ns] = __builtin_amdgcn_mfma_f32_16x16x32_bf16(af, bl, acc[ns], 0, 0, 0);
        }
    }
#pragma unroll
    for (int ns = 0; ns < 4; ++ns) {
        int col = ns * 16 + lr;
        if (col < 50) {
            float bias = b1[col];
#pragma unroll
            for (int r2 = 0; r2 < 4; ++r2) {
                int grow = m0 + w * 16 + quad * 4 + r2;
                tt[(size_t)grow * 50 + col] = __float2bfloat16(fast_tanh(acc[ns][r2] + bias));
            }
        }
    }
}

// ---------------------------------------------------------------------------
// Kernel C2: att = softmax(tt @ A2 + b2, axis=-1)   one row per lane
// ---------------------------------------------------------------------------
__global__ __launch_bounds__(256) void k_att2(
        const __hip_bfloat16* __restrict__ tt,
        const float* __restrict__ A2,
        const float* __restrict__ b2,
        float* __restrict__ att)
{
    __shared__ float A2l[600];
    __shared__ float b2l[12];
    const int tid = threadIdx.x;
    for (int idx = tid; idx < 600; idx += 256) A2l[idx] = A2[idx];
    if (tid < 12) b2l[tid] = b2[tid];
    __syncthreads();
    const int row = blockIdx.x * 256 + tid;    // 400*256 == 102400 exact
    float acc[12];
#pragma unroll
    for (int r = 0; r < 12; ++r) acc[r] = b2l[r];
    const __hip_bfloat16* trow = tt + (size_t)row * 50;
    for (int jj = 0; jj < 50; ++jj) {
        float tv = (float)trow[jj];
#pragma unroll
        for (int r = 0; r < 12; ++r) acc[r] += tv * A2l[jj * 12 + r];
    }
    float mx = acc[0];
#pragma unroll
    for (int r = 1; r < 12; ++r) mx = fmaxf(mx, acc[r]);
    float sm = 0.f;
#pragma unroll
    for (int r = 0; r < 12; ++r) { acc[r] = __expf(acc[r] - mx); sm += acc[r]; }
    float inv = 1.f / sm;
#pragma unroll
    for (int r = 0; r < 12; ++r) att[(size_t)row * 12 + r] = acc[r] * inv;
}

// ---------------------------------------------------------------------------
// Kernel D1: per-batch pooling: m = att^T h, g = att^T att, squash -> v0, nrm
// ---------------------------------------------------------------------------
__global__ __launch_bounds__(256) void k_pool(
        const __hip_bfloat16* __restrict__ h,
        const float* __restrict__ att,
        float* __restrict__ v0g,      // [128][12][192] fp32
        float* __restrict__ norms)
{
    const int b = blockIdx.x;
    const int tid = threadIdx.x;
    __shared__ __align__(16) unsigned short hT[64 * 192];
    __shared__ float attT[64 * 12];
    __shared__ float m_l[12 * 192];
    __shared__ float g_l[144];
    __shared__ float scl[12];

    float macc[12];
#pragma unroll
    for (int r = 0; r < 12; ++r) macc[r] = 0.f;
    float gacc[3] = {0.f, 0.f, 0.f};

    for (int t0 = 0; t0 < T_; t0 += 64) {
        __syncthreads();
        for (int idx = tid; idx < 64 * 96; idx += 256) {
            int rr = idx / 96, p = idx - rr * 96;
            unsigned int v = 0;
            if (t0 + rr < T_)   // zero-pad tail tile (800 = 12*64 + 32)
                v = *(const unsigned int*)((const unsigned short*)h +
                                ((size_t)(b * T_ + t0 + rr) * HC + 2 * p));
            *(unsigned int*)(&hT[rr * 192 + 2 * p]) = v;
        }
        for (int idx = tid; idx < 64 * 12; idx += 256) {
            int rr = idx / 12;
            attT[idx] = (t0 + rr < T_) ? att[(size_t)(b * T_ + t0) * 12 + idx] : 0.f;
        }
        __syncthreads();
        if (tid < 192) {
            for (int t2 = 0; t2 < 64; ++t2) {
                float hv = (float)(*(const __hip_bfloat16*)(&hT[t2 * 192 + tid]));
#pragma unroll
                for (int r = 0; r < 12; ++r) macc[r] += hv * attT[t2 * 12 + r];
            }
        } else {
            int e = tid - 192;
#pragma unroll
            for (int q = 0; q < 3; ++q) {
                int idx = e + 64 * q;
                if (idx < 144) {
                    int rr = idx / 12, ss = idx - rr * 12;
                    float s2 = 0.f;
                    for (int t2 = 0; t2 < 64; ++t2) s2 += attT[t2 * 12 + rr] * attT[t2 * 12 + ss];
                    gacc[q] += s2;
                }
            }
        }
    }
    __syncthreads();
    if (tid < 192) { for (int r = 0; r < 12; ++r) m_l[r * 192 + tid] = macc[r]; }
    else {
        int e = tid - 192;
#pragma unroll
        for (int q = 0; q < 3; ++q) { int idx = e + 64 * q; if (idx < 144) g_l[idx] = gacc[q]; }
    }
    __syncthreads();
    if (tid == 0) {
        float s2 = 0.f;
        for (int idx = 0; idx < 144; ++idx) {
            float v = g_l[idx] - ((idx / 12 == idx % 12) ? 1.f : 0.f);
            s2 += v * v;
        }
        norms[b] = sqrtf(s2);
    }
    if (tid < 12) {
        float n2 = 0.f;
        for (int i = 0; i < 192; ++i) { float v = m_l[tid * 192 + i]; n2 += v * v; }
        scl[tid] = squash_scale(n2);
    }
    __syncthreads();
    if (tid < 192) {
#pragma unroll
        for (int r = 0; r < 12; ++r)
            v0g[((size_t)b * 12 + r) * 192 + tid] = m_l[r * 192 + tid] * scl[r];
    }
}

// ---------------------------------------------------------------------------
// Kernel D2: u_hat GEMM per r: [128 x 192] @ [192 x 800]. Grid (12, 2, 13).
// ---------------------------------------------------------------------------
__global__ __launch_bounds__(256) void k_uhat(
        const float* __restrict__ v0g,
        const float* __restrict__ Wc,
        float* __restrict__ u_hat)    // [128][12][800] fp32
{
    const int r  = blockIdx.x;           // 0..11
    const int m0 = blockIdx.y * 64;      // 0,64
    const int n0 = blockIdx.z * 64;      // 0..768 (tail tile 32 valid)
    const int tid = threadIdx.x;
    __shared__ __align__(16) unsigned short At[64 * 200];
    __shared__ __align__(16) unsigned short Bt[64 * 200];
    for (int idx = tid; idx < 64 * 96; idx += 256) {
        int row = idx / 96, p = idx - row * 96;
        float2 f = *(const float2*)(v0g + ((size_t)(m0 + row) * 12 + r) * 192 + 2 * p);
        *(unsigned int*)(&At[row * 200 + 2 * p]) = pack_bf16x2(f.x, f.y);
    }
    for (int idx = tid; idx < 192 * 64; idx += 256) {
        int k = idx >> 6, nn = idx & 63;
        unsigned short v = 0;
        if (n0 + nn < 800) v = bf16_bits(Wc[((size_t)r * 192 + k) * 800 + n0 + nn]);
        Bt[nn * 200 + k] = v;
    }
    __syncthreads();
    const int w = tid >> 6, l = tid & 63;
    const int lr = l & 15, quad = l >> 4;
    f32x4 z4 = {0.f, 0.f, 0.f, 0.f};
    f32x4 acc[4];
#pragma unroll
    for (int i = 0; i < 4; ++i) acc[i] = z4;
#pragma unroll
    for (int kk = 0; kk < 6; ++kk) {
        bf16x8 af = *(const bf16x8*)(&At[(w * 16 + lr) * 200 + kk * 32 + quad * 8]);
#pragma unroll
        for (int ns = 0; ns < 4; ++ns) {
            bf16x8 bv = *(const bf16x8*)(&Bt[(ns * 16 + lr) * 200 + kk * 32 + quad * 8]);
            acc[ns] = __builtin_amdgcn_mfma_f32_16x16x32_bf16(af, bv, acc[ns], 0, 0, 0);
        }
    }
#pragma unroll
    for (int ns = 0; ns < 4; ++ns) {
        int cco = n0 + ns * 16 + lr;
        if (cco < 800) {
#pragma unroll
            for (int r2 = 0; r2 < 4; ++r2) {
                int brow = m0 + w * 16 + quad * 4 + r2;
                u_hat[((size_t)brow * 12 + r) * 800 + cco] = acc[ns][r2];
            }
        }
    }
}

// ---------------------------------------------------------------------------
// Kernel D3: dynamic routing per batch (u_hat in LDS), 3 iterations, write v.
// ---------------------------------------------------------------------------
__global__ __launch_bounds__(256) void k_route(
        const float* __restrict__ u_hat,
        float* __restrict__ out)
{
    const int b = blockIdx.x;
    const int tid = threadIdx.x;
    __shared__ __align__(16) float u_l[9600];
    __shared__ float blogl[600];
    __shared__ float c_l[600];
    __shared__ float s_l[800];
    __shared__ float v_l[800];
    __shared__ float scl[64];
    {
        const float4* src = (const float4*)(u_hat + (size_t)b * 9600);
        float4* dst = (float4*)u_l;
        for (int e = tid; e < 2400; e += 256) dst[e] = src[e];
    }
    for (int e = tid; e < 600; e += 256) blogl[e] = 0.f;
    __syncthreads();
    for (int it = 0; it < 3; ++it) {
        if (tid < 12) {
            float mx = -1e30f;
            for (int cc = 0; cc < 50; ++cc) mx = fmaxf(mx, blogl[tid * 50 + cc]);
            float sm = 0.f;
            for (int cc = 0; cc < 50; ++cc) {
                float e2 = __expf(blogl[tid * 50 + cc] - mx);
                c_l[tid * 50 + cc] = e2; sm += e2;
            }
            float inv = 1.f / sm;
            for (int cc = 0; cc < 50; ++cc) c_l[tid * 50 + cc] *= inv;
        }
        __syncthreads();
        for (int e = tid; e < 800; e += 256) {
            int cc = e >> 4;
            float sv = 0.f;
#pragma unroll
            for (int r = 0; r < 12; ++r) sv += c_l[r * 50 + cc] * u_l[r * 800 + e];
            s_l[e] = sv;
        }
        __syncthreads();
        for (int cc = tid; cc < 50; cc += 256) {
            float n2 = 0.f;
#pragma unroll
            for (int o = 0; o < 16; ++o) { float v = s_l[cc * 16 + o]; n2 += v * v; }
            scl[cc] = squash_scale(n2);
        }
        __syncthreads();
        for (int e = tid; e < 800; e += 256) v_l[e] = s_l[e] * scl[e >> 4];
        __syncthreads();
        if (it < 2) {
            for (int e = tid; e < 600; e += 256) {
                int cc = e % 50;
                float dd = 0.f;
#pragma unroll
                for (int o = 0; o < 16; ++o) dd += u_l[e * 16 + o] * v_l[cc * 16 + o];
                blogl[e] += dd;
            }
            __syncthreads();
        }
    }
    for (int e = tid; e < 800; e += 256) out[(size_t)b * 800 + e] = v_l[e];
}

// ---------------------------------------------------------------------------
// Kernel E: att_reg = mean(norms)
// ---------------------------------------------------------------------------
__global__ void k_reg(const float* __restrict__ norms, float* __restrict__ out)
{
    const int l = threadIdx.x;           // 64
    float v = norms[l] + norms[l + 64];
#pragma unroll
    for (int off = 32; off; off >>= 1) v += __shfl_down(v, off);
    if (l == 0) out[OUTV] = v * (1.f / 128.f);
}

// ---------------------------------------------------------------------------
extern "C" void kernel_launch(void* const* d_in, const int* in_sizes, int n_in,
                              void* d_out, int out_size, void* d_ws, size_t ws_size,
                              hipStream_t stream) {
    const int*   tokens = (const int*)d_in[0];
    const float* emb    = (const float*)d_in[1];
    const float* wih_f  = (const float*)d_in[2];
    const float* whh_f  = (const float*)d_in[3];
    const float* bih_f  = (const float*)d_in[4];
    const float* bhh_f  = (const float*)d_in[5];
    const float* wih_b  = (const float*)d_in[6];
    const float* whh_b  = (const float*)d_in[7];
    const float* bih_b  = (const float*)d_in[8];
    const float* bhh_b  = (const float*)d_in[9];
    const float* A1     = (const float*)d_in[10];
    const float* b1     = (const float*)d_in[11];
    const float* A2     = (const float*)d_in[12];
    const float* b2     = (const float*)d_in[13];
    const float* Wc     = (const float*)d_in[14];

    const size_t HB = 39321600;                  // hbuf: 102400*192*2 (bf16)
    const size_t GI = 58982400;                  // gi3 one dir: 128*100*2304*2
    const size_t TAIL = 11010560;
    char* ws = (char*)d_ws;
    __hip_bfloat16* hbuf = (__hip_bfloat16*)ws;
    float* out = (float*)d_out;

    if (ws_size >= HB + 2 * GI + TAIL) {
        // ---- primary: both directions resident, single merged GRU ----
        unsigned short* gi_f = (unsigned short*)(ws + HB);
        unsigned short* gi_b = (unsigned short*)(ws + HB + GI);
        char* tail = ws + HB + 2 * GI;
        __hip_bfloat16* tt   = (__hip_bfloat16*)(ws + HB);   // reuses gi_f after GRU
        float*          att  = (float*)(tail);
        float*          nrm  = (float*)(tail + 4915200);
        float*          v0g  = (float*)(tail + 4915712);
        float*          uhat = (float*)(tail + 6095360);
        k_gi2 <<<1600, 256, 0, stream>>>(tokens, emb, wih_f, wih_b, bih_f, bih_b, gi_f, gi_b, 0, 2);
        k_gru3<<<dim3(100, 2), 192, 0, stream>>>(gi_f, gi_b, whh_f, whh_b, bhh_f, bhh_b, hbuf, 0);
        k_att1 <<<1600, 256, 0, stream>>>(hbuf, A1, b1, tt);
        k_att2 <<<400, 256, 0, stream>>>(tt, A2, b2, att);
        k_pool <<<128, 256, 0, stream>>>(hbuf, att, v0g, nrm);
        k_uhat <<<dim3(12, 2, 13), 256, 0, stream>>>(v0g, Wc, uhat);
        k_route<<<128, 256, 0, stream>>>(uhat, out);
        k_reg  <<<1, 64, 0, stream>>>(nrm, out);
    } else {
        // ---- compact: one gi3 buffer, directions sequential ----
        unsigned short* gi1 = (unsigned short*)(ws + HB);
        char* tail = ws + HB + GI;
        __hip_bfloat16* tt   = (__hip_bfloat16*)(ws + HB);
        float*          att  = (float*)(tail);
        float*          nrm  = (float*)(tail + 4915200);
        float*          v0g  = (float*)(tail + 4915712);
        float*          uhat = (float*)(tail + 6095360);
        k_gi2 <<<1600, 256, 0, stream>>>(tokens, emb, wih_f, wih_b, bih_f, bih_b, gi1, gi1, 0, 1);
        k_gru3<<<dim3(100, 1), 192, 0, stream>>>(gi1, gi1, whh_f, whh_b, bhh_f, bhh_b, hbuf, 0);
        k_gi2 <<<1600, 256, 0, stream>>>(tokens, emb, wih_f, wih_b, bih_f, bih_b, gi1, gi1, 1, 1);
        k_gru3<<<dim3(100, 1), 192, 0, stream>>>(gi1, gi1, whh_f, whh_b, bhh_f, bhh_b, hbuf, 1);
        k_att1 <<<1600, 256, 0, stream>>>(hbuf, A1, b1, tt);
        k_att2 <<<400, 256, 0, stream>>>(tt, A2, b2, att);
        k_pool <<<128, 256, 0, stream>>>(hbuf, att, v0g, nrm);
        k_uhat <<<dim3(12, 2, 13), 256, 0, stream>>>(v0g, Wc, uhat);
        k_route<<<128, 256, 0, stream>>>(uhat, out);
        k_reg  <<<1, 64, 0, stream>>>(nrm, out);
    }
}

// Round 11
// 756.895 us; speedup vs baseline: 1.8744x; 1.1638x over previous
//
#include <hip/hip_runtime.h>
#include <hip/hip_bf16.h>
#include <math.h>

typedef short bf16x8 __attribute__((ext_vector_type(8)));
typedef _Float16 half8 __attribute__((ext_vector_type(8)));
typedef float f32x4 __attribute__((ext_vector_type(4)));

#define B_   128
#define T_   800
#define E_   100
#define HC   192       // 2H
#define OUTV 102400    // B*C*O

__device__ inline float squash_scale(float n2) {
    return (n2 / (n2 + 1.f)) * rsqrtf(fmaxf(n2, 1e-30f));
}

__device__ inline unsigned short bf16_bits(float x) {
    __hip_bfloat16 h = __float2bfloat16(x);
    return *(unsigned short*)&h;
}

__device__ inline unsigned int pack_bf16x2(float a, float b) {
    return (unsigned int)bf16_bits(a) | ((unsigned int)bf16_bits(b) << 16);
}

__device__ inline void split_hilo(float x, unsigned short& hi, unsigned short& lo) {
    __hip_bfloat16 h = __float2bfloat16(x);
    float hf = __bfloat162float(h);
    hi = *(unsigned short*)&h;
    __hip_bfloat16 l = __float2bfloat16(x - hf);
    lo = *(unsigned short*)&l;
}

__device__ inline float f16u_to_f(unsigned short s) {
    _Float16 h;
    __builtin_memcpy(&h, &s, 2);
    return (float)h;
}

__device__ inline unsigned short f16_bits(float x) {
    _Float16 h = (_Float16)x;
    unsigned short b;
    __builtin_memcpy(&b, &h, 2);
    return b;
}

__device__ inline unsigned int pack_f16x2(float a, float b) {
    return (unsigned int)f16_bits(a) | ((unsigned int)f16_bits(b) << 16);
}

__device__ inline float fast_sigmoid(float x) { return 1.f / (1.f + __expf(-x)); }
__device__ inline float fast_tanh(float x) {
    float e = __expf(2.f * x);
    return 1.f - 2.f / (e + 1.f);
}

// ---------------------------------------------------------------------------
// Kernel A (v3): gi for both directions, one block per 64-row m-tile.
// f16 single-plane A (emb) and B (wih) -> LDS 71,680 B -> 2 blocks/CU
// (v2's 89,600 B hi/lo variant collapsed to 1 block/CU = 4 waves, latency-
// bound at 375 us with all pipes <11%). One MFMA per fragment. C tile staged
// in LDS in gi3 group layout, then dense coalesced uint4 copy (keeps the
// round-10-verified write-amplification fix: WRITE 115 MB = payload).
// ---------------------------------------------------------------------------
__global__ __launch_bounds__(256) void k_gi2(const int* __restrict__ tokens,
        const float* __restrict__ emb,
        const float* __restrict__ wih0, const float* __restrict__ wih1,
        const float* __restrict__ bih0, const float* __restrict__ bih1,
        unsigned short* __restrict__ g3_0, unsigned short* __restrict__ g3_1,
        int uoff, int ndir)
{
    const int m0 = blockIdx.x * 64;      // 1600 blocks
    const int tid = threadIdx.x;
    __shared__ __align__(16) unsigned short At[64 * 136];     // f16 emb tile
    __shared__ __align__(16) unsigned short Bt[64 * 136];     // f16 wih tile
    __shared__ __align__(16) unsigned short outb[8 * 2304];   // 36,864 B
    __shared__ int tok[64];
    if (tid < 64) tok[tid] = tokens[m0 + tid];
    __syncthreads();
    // stage A tile once (emb gather, f16 single plane)
    for (int idx = tid; idx < 64 * 64; idx += 256) {
        int r = idx >> 6, p = idx & 63;
        unsigned int v = 0;
        if (p < 50) {
            float2 f = *(const float2*)(emb + (size_t)tok[r] * E_ + 2 * p);
            v = pack_f16x2(f.x, f.y);
        }
        *(unsigned int*)(&At[r * 136 + 2 * p]) = v;
    }
    const int w = tid >> 6, l = tid & 63;
    const int lr = l & 15, quad = l >> 4;
    const int group_local = w * 2 + (quad >> 1);
    const int lane_g = ((quad & 1) << 4) + lr;

    for (int uu = uoff; uu < uoff + ndir; ++uu) {
        const float* wih = uu ? wih1 : wih0;
        const float* bih = uu ? bih1 : bih0;
        unsigned short* gi3 = uu ? g3_1 : g3_0;
        for (int nt = 0; nt < 5; ++nt) {
            const int n0 = nt * 64;
            __syncthreads();             // prev B reads + prev outb copy done
            for (int idx = tid; idx < 64 * 64; idx += 256) {
                int nn = idx >> 6, p = idx & 63;
                int gc = n0 + nn;
                unsigned int v = 0;
                if (p < 50 && gc < 288) {
                    float2 f = *(const float2*)(wih + (size_t)gc * E_ + 2 * p);
                    v = pack_f16x2(f.x, f.y);
                }
                *(unsigned int*)(&Bt[nn * 136 + 2 * p]) = v;
            }
            __syncthreads();
            f32x4 z4 = {0.f, 0.f, 0.f, 0.f};
            f32x4 acc[4];
#pragma unroll
            for (int i = 0; i < 4; ++i) acc[i] = z4;
#pragma unroll
            for (int kk = 0; kk < 4; ++kk) {
                half8 af = *(const half8*)(&At[(w * 16 + lr) * 136 + kk * 32 + quad * 8]);
#pragma unroll
                for (int ns = 0; ns < 4; ++ns) {
                    half8 bv = *(const half8*)(&Bt[(ns * 16 + lr) * 136 + kk * 32 + quad * 8]);
                    acc[ns] = __builtin_amdgcn_mfma_f32_16x16x32_f16(af, bv, acc[ns], 0, 0, 0);
                }
            }
            // stage C fragments into outb (gi3 layout); 4 r2 are contiguous
#pragma unroll
            for (int ns = 0; ns < 4; ++ns) {
                int gcol = n0 + ns * 16 + lr;     // c16 == lr
                if (gcol < 288) {
                    float bias = bih[gcol];
                    int g = (gcol >= 192) ? 2 : (gcol >= 96 ? 1 : 0);
                    int j = gcol - g * 96;
                    int tt = j >> 4, wv3 = tt >> 1, pp = tt & 1;
                    unsigned short* dst = &outb[group_local * 2304 + wv3 * 768
                                                + lane_g * 24 + (pp * 3 + g) * 4];
                    unsigned int w0 = pack_f16x2(acc[ns][0] + bias, acc[ns][1] + bias);
                    unsigned int w1 = pack_f16x2(acc[ns][2] + bias, acc[ns][3] + bias);
                    *(unsigned int*)(dst) = w0;
                    *(unsigned int*)(dst + 2) = w1;
                }
            }
        }
        __syncthreads();                 // outb complete
        // dense coalesced copy: 36,864 B -> gi3 region of this m-tile
        const uint4* src = (const uint4*)outb;
        uint4* dst = (uint4*)(gi3 + (size_t)(m0 >> 3) * 2304);
        for (int e = tid; e < 2304; e += 256) dst[e] = src[e];
    }
}

// ---------------------------------------------------------------------------
// Kernel B: MFMA GRU (round-9 verified). Grid (100, ndir) x 192 threads.
// ---------------------------------------------------------------------------
__global__ __launch_bounds__(192, 1) void k_gru3(
        const unsigned short* __restrict__ gi3_f,
        const unsigned short* __restrict__ gi3_b,
        const float* __restrict__ whh_f, const float* __restrict__ whh_b,
        const float* __restrict__ bhh_f, const float* __restrict__ bhh_b,
        __hip_bfloat16* __restrict__ hout, int uoff)
{
    const int blk = blockIdx.x;          // 0..99
    const int u = blockIdx.y + uoff;     // 0 fwd, 1 bwd
    const int tid = threadIdx.x;
    const int wv = tid >> 6, lane = tid & 63;
    const int c16 = lane & 15, quad = lane >> 4;
    const unsigned short* gi3 = u ? gi3_b : gi3_f;
    const float* whh = u ? whh_b : whh_f;
    const float* bhh = u ? bhh_b : bhh_f;

    __shared__ _Float16 h16[16 * 104];   // rows 8..15 stay zero (M pad)

    half8 bf[2][3][3];                   // [pair][gate][kchunk]
    float bias[2][3];
#pragma unroll
    for (int pp = 0; pp < 2; ++pp)
#pragma unroll
        for (int g = 0; g < 3; ++g) {
            int n = g * 96 + (2 * wv + pp) * 16 + c16;
            bias[pp][g] = bhh[n];
#pragma unroll
            for (int kc = 0; kc < 3; ++kc) {
                const float* wp = whh + (size_t)n * 96 + kc * 32 + quad * 8;
                half8 hb;
#pragma unroll
                for (int e = 0; e < 8; ++e) hb[e] = (_Float16)wp[e];
                bf[pp][g][kc] = hb;
            }
        }

    for (int idx = tid; idx < 16 * 104; idx += 192) h16[idx] = (_Float16)0.f;
    float hst[2][4];
#pragma unroll
    for (int pp = 0; pp < 2; ++pp)
#pragma unroll
        for (int rg = 0; rg < 4; ++rg) hst[pp][rg] = 0.f;
    __syncthreads();

    const int valid = (lane < 32);
    const size_t wvlane = (size_t)wv * 768 + (size_t)lane * 24;

    uint4 cur0, cur1, cur2;
    {
        int i0 = u ? 127 : 0;
        if (valid) {
            const uint4* p = (const uint4*)(gi3 + ((size_t)i0 * 100 + blk) * 2304 + wvlane);
            cur0 = p[0]; cur1 = p[1]; cur2 = p[2];
        }
    }

    for (int s = 0; s < 128; ++s) {
        const int i = u ? (127 - s) : s;
        half8 a0 = *(const half8*)(&h16[c16 * 104 + 0  + quad * 8]);
        half8 a1 = *(const half8*)(&h16[c16 * 104 + 32 + quad * 8]);
        half8 a2 = *(const half8*)(&h16[c16 * 104 + 64 + quad * 8]);
        f32x4 acc[2][3];
#pragma unroll
        for (int pp = 0; pp < 2; ++pp)
#pragma unroll
            for (int g = 0; g < 3; ++g) {
                f32x4 c = {0.f, 0.f, 0.f, 0.f};
                c = __builtin_amdgcn_mfma_f32_16x16x32_f16(a0, bf[pp][g][0], c, 0, 0, 0);
                c = __builtin_amdgcn_mfma_f32_16x16x32_f16(a1, bf[pp][g][1], c, 0, 0, 0);
                c = __builtin_amdgcn_mfma_f32_16x16x32_f16(a2, bf[pp][g][2], c, 0, 0, 0);
                acc[pp][g] = c;
            }
        uint4 nx0, nx1, nx2;
        {
            int inx = (s < 127) ? (u ? i - 1 : i + 1) : i;
            if (valid) {
                const uint4* p = (const uint4*)(gi3 + ((size_t)inx * 100 + blk) * 2304 + wvlane);
                nx0 = p[0]; nx1 = p[1]; nx2 = p[2];
            }
        }
        __syncthreads();
        if (valid) {
            unsigned int cw[12];
            *(uint4*)(&cw[0]) = cur0; *(uint4*)(&cw[4]) = cur1; *(uint4*)(&cw[8]) = cur2;
#pragma unroll
            for (int pp = 0; pp < 2; ++pp) {
                const int j = (2 * wv + pp) * 16 + c16;
#pragma unroll
                for (int rg = 0; rg < 4; ++rg) {
                    int ir_ = (pp * 3 + 0) * 4 + rg;
                    int iz_ = (pp * 3 + 1) * 4 + rg;
                    int in_ = (pp * 3 + 2) * 4 + rg;
                    float gr = f16u_to_f((unsigned short)((ir_ & 1) ? (cw[ir_ >> 1] >> 16) : (cw[ir_ >> 1] & 0xffff)));
                    float gz = f16u_to_f((unsigned short)((iz_ & 1) ? (cw[iz_ >> 1] >> 16) : (cw[iz_ >> 1] & 0xffff)));
                    float gn = f16u_to_f((unsigned short)((in_ & 1) ? (cw[in_ >> 1] >> 16) : (cw[in_ >> 1] & 0xffff)));
                    float hr = acc[pp][0][rg] + bias[pp][0];
                    float hz = acc[pp][1][rg] + bias[pp][1];
                    float hn = acc[pp][2][rg] + bias[pp][2];
                    float r = fast_sigmoid(gr + hr);
                    float z = fast_sigmoid(gz + hz);
                    float nn = fast_tanh(gn + r * hn);
                    float hp = (1.f - z) * nn + z * hst[pp][rg];
                    hst[pp][rg] = hp;
                    int m = quad * 4 + rg;
                    h16[m * 104 + j] = (_Float16)hp;
                    int t = blk * 8 + m;
                    hout[((size_t)i * T_ + t) * HC + u * 96 + j] = __float2bfloat16(hp);
                }
            }
        }
        __syncthreads();
        cur0 = nx0; cur1 = nx1; cur2 = nx2;
    }
}

// ---------------------------------------------------------------------------
// Kernel C1: tt = tanh(h @ A1 + b1)    M=102400, K=192, N=50 (pad 64), MFMA
// ---------------------------------------------------------------------------
__global__ __launch_bounds__(256) void k_att1(
        const __hip_bfloat16* __restrict__ h,
        const float* __restrict__ A1,
        const float* __restrict__ b1,
        __hip_bfloat16* __restrict__ tt)
{
    const int m0 = blockIdx.x * 64;      // 1600 blocks
    const int tid = threadIdx.x;
    __shared__ __align__(16) unsigned short At[64 * 200];
    __shared__ __align__(16) unsigned short Bhi[64 * 200];
    __shared__ __align__(16) unsigned short Blo[64 * 200];
    for (int idx = tid; idx < 64 * 96; idx += 256) {
        int r = idx / 96, p = idx - r * 96;
        unsigned int v = *(const unsigned int*)((const unsigned short*)h + ((size_t)(m0 + r) * HC + 2 * p));
        *(unsigned int*)(&At[r * 200 + 2 * p]) = v;
    }
    for (int idx = tid; idx < 64 * 192; idx += 256) {
        int nn = idx / 192, k = idx - nn * 192;
        unsigned short vh = 0, vl = 0;
        if (nn < 50) split_hilo(A1[k * 50 + nn], vh, vl);   // transpose A1 -> B[n][k]
        Bhi[nn * 200 + k] = vh;
        Blo[nn * 200 + k] = vl;
    }
    __syncthreads();
    const int w = tid >> 6, l = tid & 63;
    const int lr = l & 15, quad = l >> 4;
    f32x4 z4 = {0.f, 0.f, 0.f, 0.f};
    f32x4 acc[4];
#pragma unroll
    for (int i = 0; i < 4; ++i) acc[i] = z4;
#pragma unroll
    for (int kk = 0; kk < 6; ++kk) {
        bf16x8 af = *(const bf16x8*)(&At[(w * 16 + lr) * 200 + kk * 32 + quad * 8]);
#pragma unroll
        for (int ns = 0; ns < 4; ++ns) {
            bf16x8 bh = *(const bf16x8*)(&Bhi[(ns * 16 + lr) * 200 + kk * 32 + quad * 8]);
            bf16x8 bl = *(const bf16x8*)(&Blo[(ns * 16 + lr) * 200 + kk * 32 + quad * 8]);
            acc[ns] = __builtin_amdgcn_mfma_f32_16x16x32_bf16(af, bh, acc[ns], 0, 0, 0);
            acc[ns] = __builtin_amdgcn_mfma_f32_16x16x32_bf16(af, bl, acc[ns], 0, 0, 0);
        }
    }
#pragma unroll
    for (int ns = 0; ns < 4; ++ns) {
        int col = ns * 16 + lr;
        if (col < 50) {
            float bias = b1[col];
#pragma unroll
            for (int r2 = 0; r2 < 4; ++r2) {
                int grow = m0 + w * 16 + quad * 4 + r2;
                tt[(size_t)grow * 50 + col] = __float2bfloat16(fast_tanh(acc[ns][r2] + bias));
            }
        }
    }
}

// ---------------------------------------------------------------------------
// Kernel C2: att = softmax(tt @ A2 + b2, axis=-1)   one row per lane
// ---------------------------------------------------------------------------
__global__ __launch_bounds__(256) void k_att2(
        const __hip_bfloat16* __restrict__ tt,
        const float* __restrict__ A2,
        const float* __restrict__ b2,
        float* __restrict__ att)
{
    __shared__ float A2l[600];
    __shared__ float b2l[12];
    const int tid = threadIdx.x;
    for (int idx = tid; idx < 600; idx += 256) A2l[idx] = A2[idx];
    if (tid < 12) b2l[tid] = b2[tid];
    __syncthreads();
    const int row = blockIdx.x * 256 + tid;    // 400*256 == 102400 exact
    float acc[12];
#pragma unroll
    for (int r = 0; r < 12; ++r) acc[r] = b2l[r];
    const __hip_bfloat16* trow = tt + (size_t)row * 50;
    for (int jj = 0; jj < 50; ++jj) {
        float tv = (float)trow[jj];
#pragma unroll
        for (int r = 0; r < 12; ++r) acc[r] += tv * A2l[jj * 12 + r];
    }
    float mx = acc[0];
#pragma unroll
    for (int r = 1; r < 12; ++r) mx = fmaxf(mx, acc[r]);
    float sm = 0.f;
#pragma unroll
    for (int r = 0; r < 12; ++r) { acc[r] = __expf(acc[r] - mx); sm += acc[r]; }
    float inv = 1.f / sm;
#pragma unroll
    for (int r = 0; r < 12; ++r) att[(size_t)row * 12 + r] = acc[r] * inv;
}

// ---------------------------------------------------------------------------
// Kernel D1: per-batch pooling: m = att^T h, g = att^T att, squash -> v0, nrm
// ---------------------------------------------------------------------------
__global__ __launch_bounds__(256) void k_pool(
        const __hip_bfloat16* __restrict__ h,
        const float* __restrict__ att,
        float* __restrict__ v0g,      // [128][12][192] fp32
        float* __restrict__ norms)
{
    const int b = blockIdx.x;
    const int tid = threadIdx.x;
    __shared__ __align__(16) unsigned short hT[64 * 192];
    __shared__ float attT[64 * 12];
    __shared__ float m_l[12 * 192];
    __shared__ float g_l[144];
    __shared__ float scl[12];

    float macc[12];
#pragma unroll
    for (int r = 0; r < 12; ++r) macc[r] = 0.f;
    float gacc[3] = {0.f, 0.f, 0.f};

    for (int t0 = 0; t0 < T_; t0 += 64) {
        __syncthreads();
        for (int idx = tid; idx < 64 * 96; idx += 256) {
            int rr = idx / 96, p = idx - rr * 96;
            unsigned int v = 0;
            if (t0 + rr < T_)   // zero-pad tail tile (800 = 12*64 + 32)
                v = *(const unsigned int*)((const unsigned short*)h +
                                ((size_t)(b * T_ + t0 + rr) * HC + 2 * p));
            *(unsigned int*)(&hT[rr * 192 + 2 * p]) = v;
        }
        for (int idx = tid; idx < 64 * 12; idx += 256) {
            int rr = idx / 12;
            attT[idx] = (t0 + rr < T_) ? att[(size_t)(b * T_ + t0) * 12 + idx] : 0.f;
        }
        __syncthreads();
        if (tid < 192) {
            for (int t2 = 0; t2 < 64; ++t2) {
                float hv = (float)(*(const __hip_bfloat16*)(&hT[t2 * 192 + tid]));
#pragma unroll
                for (int r = 0; r < 12; ++r) macc[r] += hv * attT[t2 * 12 + r];
            }
        } else {
            int e = tid - 192;
#pragma unroll
            for (int q = 0; q < 3; ++q) {
                int idx = e + 64 * q;
                if (idx < 144) {
                    int rr = idx / 12, ss = idx - rr * 12;
                    float s2 = 0.f;
                    for (int t2 = 0; t2 < 64; ++t2) s2 += attT[t2 * 12 + rr] * attT[t2 * 12 + ss];
                    gacc[q] += s2;
                }
            }
        }
    }
    __syncthreads();
    if (tid < 192) { for (int r = 0; r < 12; ++r) m_l[r * 192 + tid] = macc[r]; }
    else {
        int e = tid - 192;
#pragma unroll
        for (int q = 0; q < 3; ++q) { int idx = e + 64 * q; if (idx < 144) g_l[idx] = gacc[q]; }
    }
    __syncthreads();
    if (tid == 0) {
        float s2 = 0.f;
        for (int idx = 0; idx < 144; ++idx) {
            float v = g_l[idx] - ((idx / 12 == idx % 12) ? 1.f : 0.f);
            s2 += v * v;
        }
        norms[b] = sqrtf(s2);
    }
    if (tid < 12) {
        float n2 = 0.f;
        for (int i = 0; i < 192; ++i) { float v = m_l[tid * 192 + i]; n2 += v * v; }
        scl[tid] = squash_scale(n2);
    }
    __syncthreads();
    if (tid < 192) {
#pragma unroll
        for (int r = 0; r < 12; ++r)
            v0g[((size_t)b * 12 + r) * 192 + tid] = m_l[r * 192 + tid] * scl[r];
    }
}

// ---------------------------------------------------------------------------
// Kernel D2: u_hat GEMM per r: [128 x 192] @ [192 x 800]. Grid (12, 2, 13).
// ---------------------------------------------------------------------------
__global__ __launch_bounds__(256) void k_uhat(
        const float* __restrict__ v0g,
        const float* __restrict__ Wc,
        float* __restrict__ u_hat)    // [128][12][800] fp32
{
    const int r  = blockIdx.x;           // 0..11
    const int m0 = blockIdx.y * 64;      // 0,64
    const int n0 = blockIdx.z * 64;      // 0..768 (tail tile 32 valid)
    const int tid = threadIdx.x;
    __shared__ __align__(16) unsigned short At[64 * 200];
    __shared__ __align__(16) unsigned short Bt[64 * 200];
    for (int idx = tid; idx < 64 * 96; idx += 256) {
        int row = idx / 96, p = idx - row * 96;
        float2 f = *(const float2*)(v0g + ((size_t)(m0 + row) * 12 + r) * 192 + 2 * p);
        *(unsigned int*)(&At[row * 200 + 2 * p]) = pack_bf16x2(f.x, f.y);
    }
    for (int idx = tid; idx < 192 * 64; idx += 256) {
        int k = idx >> 6, nn = idx & 63;
        unsigned short v = 0;
        if (n0 + nn < 800) v = bf16_bits(Wc[((size_t)r * 192 + k) * 800 + n0 + nn]);
        Bt[nn * 200 + k] = v;
    }
    __syncthreads();
    const int w = tid >> 6, l = tid & 63;
    const int lr = l & 15, quad = l >> 4;
    f32x4 z4 = {0.f, 0.f, 0.f, 0.f};
    f32x4 acc[4];
#pragma unroll
    for (int i = 0; i < 4; ++i) acc[i] = z4;
#pragma unroll
    for (int kk = 0; kk < 6; ++kk) {
        bf16x8 af = *(const bf16x8*)(&At[(w * 16 + lr) * 200 + kk * 32 + quad * 8]);
#pragma unroll
        for (int ns = 0; ns < 4; ++ns) {
            bf16x8 bv = *(const bf16x8*)(&Bt[(ns * 16 + lr) * 200 + kk * 32 + quad * 8]);
            acc[ns] = __builtin_amdgcn_mfma_f32_16x16x32_bf16(af, bv, acc[ns], 0, 0, 0);
        }
    }
#pragma unroll
    for (int ns = 0; ns < 4; ++ns) {
        int cco = n0 + ns * 16 + lr;
        if (cco < 800) {
#pragma unroll
            for (int r2 = 0; r2 < 4; ++r2) {
                int brow = m0 + w * 16 + quad * 4 + r2;
                u_hat[((size_t)brow * 12 + r) * 800 + cco] = acc[ns][r2];
            }
        }
    }
}

// ---------------------------------------------------------------------------
// Kernel D3: dynamic routing per batch (u_hat in LDS), 3 iterations, write v.
// ---------------------------------------------------------------------------
__global__ __launch_bounds__(256) void k_route(
        const float* __restrict__ u_hat,
        float* __restrict__ out)
{
    const int b = blockIdx.x;
    const int tid = threadIdx.x;
    __shared__ __align__(16) float u_l[9600];
    __shared__ float blogl[600];
    __shared__ float c_l[600];
    __shared__ float s_l[800];
    __shared__ float v_l[800];
    __shared__ float scl[64];
    {
        const float4* src = (const float4*)(u_hat + (size_t)b * 9600);
        float4* dst = (float4*)u_l;
        for (int e = tid; e < 2400; e += 256) dst[e] = src[e];
    }
    for (int e = tid; e < 600; e += 256) blogl[e] = 0.f;
    __syncthreads();
    for (int it = 0; it < 3; ++it) {
        if (tid < 12) {
            float mx = -1e30f;
            for (int cc = 0; cc < 50; ++cc) mx = fmaxf(mx, blogl[tid * 50 + cc]);
            float sm = 0.f;
            for (int cc = 0; cc < 50; ++cc) {
                float e2 = __expf(blogl[tid * 50 + cc] - mx);
                c_l[tid * 50 + cc] = e2; sm += e2;
            }
            float inv = 1.f / sm;
            for (int cc = 0; cc < 50; ++cc) c_l[tid * 50 + cc] *= inv;
        }
        __syncthreads();
        for (int e = tid; e < 800; e += 256) {
            int cc = e >> 4;
            float sv = 0.f;
#pragma unroll
            for (int r = 0; r < 12; ++r) sv += c_l[r * 50 + cc] * u_l[r * 800 + e];
            s_l[e] = sv;
        }
        __syncthreads();
        for (int cc = tid; cc < 50; cc += 256) {
            float n2 = 0.f;
#pragma unroll
            for (int o = 0; o < 16; ++o) { float v = s_l[cc * 16 + o]; n2 += v * v; }
            scl[cc] = squash_scale(n2);
        }
        __syncthreads();
        for (int e = tid; e < 800; e += 256) v_l[e] = s_l[e] * scl[e >> 4];
        __syncthreads();
        if (it < 2) {
            for (int e = tid; e < 600; e += 256) {
                int cc = e % 50;
                float dd = 0.f;
#pragma unroll
                for (int o = 0; o < 16; ++o) dd += u_l[e * 16 + o] * v_l[cc * 16 + o];
                blogl[e] += dd;
            }
            __syncthreads();
        }
    }
    for (int e = tid; e < 800; e += 256) out[(size_t)b * 800 + e] = v_l[e];
}

// ---------------------------------------------------------------------------
// Kernel E: att_reg = mean(norms)
// ---------------------------------------------------------------------------
__global__ void k_reg(const float* __restrict__ norms, float* __restrict__ out)
{
    const int l = threadIdx.x;           // 64
    float v = norms[l] + norms[l + 64];
#pragma unroll
    for (int off = 32; off; off >>= 1) v += __shfl_down(v, off);
    if (l == 0) out[OUTV] = v * (1.f / 128.f);
}

// ---------------------------------------------------------------------------
extern "C" void kernel_launch(void* const* d_in, const int* in_sizes, int n_in,
                              void* d_out, int out_size, void* d_ws, size_t ws_size,
                              hipStream_t stream) {
    const int*   tokens = (const int*)d_in[0];
    const float* emb    = (const float*)d_in[1];
    const float* wih_f  = (const float*)d_in[2];
    const float* whh_f  = (const float*)d_in[3];
    const float* bih_f  = (const float*)d_in[4];
    const float* bhh_f  = (const float*)d_in[5];
    const float* wih_b  = (const float*)d_in[6];
    const float* whh_b  = (const float*)d_in[7];
    const float* bih_b  = (const float*)d_in[8];
    const float* bhh_b  = (const float*)d_in[9];
    const float* A1     = (const float*)d_in[10];
    const float* b1     = (const float*)d_in[11];
    const float* A2     = (const float*)d_in[12];
    const float* b2     = (const float*)d_in[13];
    const float* Wc     = (const float*)d_in[14];

    const size_t HB = 39321600;                  // hbuf: 102400*192*2 (bf16)
    const size_t GI = 58982400;                  // gi3 one dir: 128*100*2304*2
    const size_t TAIL = 11010560;
    char* ws = (char*)d_ws;
    __hip_bfloat16* hbuf = (__hip_bfloat16*)ws;
    float* out = (float*)d_out;

    if (ws_size >= HB + 2 * GI + TAIL) {
        // ---- primary: both directions resident, single merged GRU ----
        unsigned short* gi_f = (unsigned short*)(ws + HB);
        unsigned short* gi_b = (unsigned short*)(ws + HB + GI);
        char* tail = ws + HB + 2 * GI;
        __hip_bfloat16* tt   = (__hip_bfloat16*)(ws + HB);   // reuses gi_f after GRU
        float*          att  = (float*)(tail);
        float*          nrm  = (float*)(tail + 4915200);
        float*          v0g  = (float*)(tail + 4915712);
        float*          uhat = (float*)(tail + 6095360);
        k_gi2 <<<1600, 256, 0, stream>>>(tokens, emb, wih_f, wih_b, bih_f, bih_b, gi_f, gi_b, 0, 2);
        k_gru3<<<dim3(100, 2), 192, 0, stream>>>(gi_f, gi_b, whh_f, whh_b, bhh_f, bhh_b, hbuf, 0);
        k_att1 <<<1600, 256, 0, stream>>>(hbuf, A1, b1, tt);
        k_att2 <<<400, 256, 0, stream>>>(tt, A2, b2, att);
        k_pool <<<128, 256, 0, stream>>>(hbuf, att, v0g, nrm);
        k_uhat <<<dim3(12, 2, 13), 256, 0, stream>>>(v0g, Wc, uhat);
        k_route<<<128, 256, 0, stream>>>(uhat, out);
        k_reg  <<<1, 64, 0, stream>>>(nrm, out);
    } else {
        // ---- compact: one gi3 buffer, directions sequential ----
        unsigned short* gi1 = (unsigned short*)(ws + HB);
        char* tail = ws + HB + GI;
        __hip_bfloat16* tt   = (__hip_bfloat16*)(ws + HB);
        float*          att  = (float*)(tail);
        float*          nrm  = (float*)(tail + 4915200);
        float*          v0g  = (float*)(tail + 4915712);
        float*          uhat = (float*)(tail + 6095360);
        k_gi2 <<<1600, 256, 0, stream>>>(tokens, emb, wih_f, wih_b, bih_f, bih_b, gi1, gi1, 0, 1);
        k_gru3<<<dim3(100, 1), 192, 0, stream>>>(gi1, gi1, whh_f, whh_b, bhh_f, bhh_b, hbuf, 0);
        k_gi2 <<<1600, 256, 0, stream>>>(tokens, emb, wih_f, wih_b, bih_f, bih_b, gi1, gi1, 1, 1);
        k_gru3<<<dim3(100, 1), 192, 0, stream>>>(gi1, gi1, whh_f, whh_b, bhh_f, bhh_b, hbuf, 1);
        k_att1 <<<1600, 256, 0, stream>>>(hbuf, A1, b1, tt);
        k_att2 <<<400, 256, 0, stream>>>(tt, A2, b2, att);
        k_pool <<<128, 256, 0, stream>>>(hbuf, att, v0g, nrm);
        k_uhat <<<dim3(12, 2, 13), 256, 0, stream>>>(v0g, Wc, uhat);
        k_route<<<128, 256, 0, stream>>>(uhat, out);
        k_reg  <<<1, 64, 0, stream>>>(nrm, out);
    }
}